// Round 8
// baseline (933.881 us; speedup 1.0000x reference)
//
#include <hip/hip_runtime.h>
#include <hip/hip_bf16.h>
#include <cstdint>
#include <cstddef>

#define NN 50000
#define NE 800000
#define NRBP 3128  // padded row-chunk count: ceil(50000/16)=3125 -> pad to mult of 8
#define NBK 196    // coarse buckets: dest >> 8  (50000/256 -> 196)

typedef __attribute__((ext_vector_type(8))) short bf16x8;
typedef __attribute__((ext_vector_type(4))) float f32x4;
typedef __attribute__((ext_vector_type(4))) unsigned short u16x4;

static __device__ __forceinline__ unsigned short f2bf_u(float f) {
    __hip_bfloat16 h = __float2bfloat16(f);
    return *reinterpret_cast<unsigned short*>(&h);
}
static __device__ __forceinline__ float bfu2f(unsigned short u) {
    __hip_bfloat16 h = *reinterpret_cast<__hip_bfloat16*>(&u);
    return __bfloat162float(h);
}

// async global->LDS, 16B per lane. lds dst must be wave-uniform (HW adds lane*16).
static __device__ __forceinline__ void gll16(void* lds_dst, const void* gsrc) {
    __builtin_amdgcn_global_load_lds(
        (const __attribute__((address_space(1))) void*)gsrc,
        (__attribute__((address_space(3))) void*)lds_dst, 16, 0, 0);
}

// ================= CSR build: bucket sort (LDS-localized, low atomic thrash) ====

__global__ __launch_bounds__(256) void k_bhist(const int* __restrict__ ecol,
                                               int* __restrict__ bcnt, int e) {
    __shared__ int lcnt[NBK];
    int tid = threadIdx.x;
    for (int t = tid; t < NBK; t += 256) lcnt[t] = 0;
    __syncthreads();
#pragma unroll
    for (int q = 0; q < 4; ++q) {
        int i = blockIdx.x * 1024 + q * 256 + tid;
        if (i < e) atomicAdd(&lcnt[ecol[i] >> 8], 1);
    }
    __syncthreads();
    for (int t = tid; t < NBK; t += 256)
        if (lcnt[t]) atomicAdd(&bcnt[t], lcnt[t]);
}

__global__ void k_bscan(const int* __restrict__ bcnt, int* __restrict__ boff,
                        int* __restrict__ gcur, int* __restrict__ rowptr) {
    int tid = threadIdx.x;
    int v = (tid < NBK) ? bcnt[tid] : 0;
    int lane = tid & 63, w = tid >> 6;
    int incl = v;
#pragma unroll
    for (int d = 1; d < 64; d <<= 1) {
        int t = __shfl_up(incl, d);
        if (lane >= d) incl += t;
    }
    __shared__ int wsum[4];
    if (lane == 63) wsum[w] = incl;
    __syncthreads();
    int woff = 0;
    for (int j = 0; j < w; ++j) woff += wsum[j];
    int ex = woff + incl - v;
    if (tid < NBK) { boff[tid] = ex; gcur[tid] = ex; }
    if (tid == 255) { boff[NBK] = ex; rowptr[NN] = ex; }  // == E
}

__global__ __launch_bounds__(256) void k_bscat(const int* __restrict__ erow,
                                               const int* __restrict__ ecol,
                                               const float* __restrict__ eval_,
                                               int* __restrict__ gcur,
                                               int2* __restrict__ tmp, int e) {
    __shared__ int lcnt[NBK], lbase[NBK], lcur[NBK];
    int tid = threadIdx.x;
    for (int t = tid; t < NBK; t += 256) { lcnt[t] = 0; lcur[t] = 0; }
    __syncthreads();
    int d_[4], b_[4];
#pragma unroll
    for (int q = 0; q < 4; ++q) {
        int i = blockIdx.x * 1024 + q * 256 + tid;
        d_[q] = -1;
        if (i < e) {
            d_[q] = ecol[i];
            b_[q] = d_[q] >> 8;
            atomicAdd(&lcnt[b_[q]], 1);
        }
    }
    __syncthreads();
    for (int t = tid; t < NBK; t += 256)
        lbase[t] = lcnt[t] ? atomicAdd(&gcur[t], lcnt[t]) : 0;
    __syncthreads();
#pragma unroll
    for (int q = 0; q < 4; ++q) {
        int i = blockIdx.x * 1024 + q * 256 + tid;
        if (i < e) {
            int b = b_[q];
            int pos = lbase[b] + atomicAdd(&lcur[b], 1);
            tmp[pos] = make_int2(erow[i] | ((d_[q] & 255) << 20), __float_as_int(eval_[i]));
        }
    }
}

__global__ __launch_bounds__(256) void k_bsort(const int2* __restrict__ tmp,
                                               const int* __restrict__ boff,
                                               int* __restrict__ rowptr,
                                               float* __restrict__ dinv,
                                               int2* __restrict__ epk) {
    __shared__ int lcnt[256], lcur[256];
    __shared__ float ldeg[256];
    __shared__ int wsum[4];
    int tid = threadIdx.x;
    int b = blockIdx.x;
    int base = boff[b], endb = boff[b + 1];
    lcnt[tid] = 0;
    ldeg[tid] = 0.f;
    __syncthreads();
    for (int i = base + tid; i < endb; i += 256) {
        int2 e2 = tmp[i];
        int d = e2.x >> 20;
        atomicAdd(&lcnt[d], 1);
        atomicAdd(&ldeg[d], __int_as_float(e2.y));
    }
    __syncthreads();
    int v = lcnt[tid];
    int lane = tid & 63, w = tid >> 6;
    int incl = v;
#pragma unroll
    for (int d = 1; d < 64; d <<= 1) {
        int t = __shfl_up(incl, d);
        if (lane >= d) incl += t;
    }
    if (lane == 63) wsum[w] = incl;
    __syncthreads();
    int woff = 0;
    for (int j = 0; j < w; ++j) woff += wsum[j];
    int ex = woff + incl - v;
    int dest = (b << 8) + tid;
    if (dest < NN) {
        rowptr[dest] = base + ex;
        dinv[dest] = rsqrtf(1.f + ldeg[tid]);
    }
    lcur[tid] = ex;
    __syncthreads();
    for (int i = base + tid; i < endb; i += 256) {
        int2 e2 = tmp[i];
        int d = e2.x >> 20;
        int pos = base + atomicAdd(&lcur[d], 1);
        epk[pos] = make_int2(e2.x & 0xFFFFF, e2.y);
    }
}

// epk.y := raw_val * dinv[src]  (dst factor applied in agg)
__global__ void k_normw(int2* __restrict__ epk, const float* __restrict__ dinv, int e) {
    int i = blockIdx.x * 256 + threadIdx.x;
    if (i < e) {
        int2 pk = epk[i];
        epk[i].y = __float_as_int(__int_as_float(pk.y) * dinv[pk.x]);
    }
}

// ====== sparse aggregation: XCD-pinned column slices, direct group gather =======
// slice = blockIdx % 8 -> all blocks of a slice land on one XCD (round-robin
// dispatch), whose L2 holds H[:, slice] (3.2 MB for DIM=256). Lanes form groups
// of LPG; group g walks edges beg+g, beg+g+GPW, ... reading epk[e] directly
// (group-uniform address -> HW broadcast; non-temporal so streams don't evict H).
// Cross-group shfl_xor reduce at the end; group 0 writes.
// out[i,:] = dinv_i*(dinv_i*H[i,:] + sum_e w'_e*H[src_e,:]) + bias (opt relu)
template<int DIM, bool RELU, bool FRAGOUT>
__global__ __launch_bounds__(256) void k_aggs(const unsigned short* __restrict__ H,
        const int* __restrict__ rowptr, const int2* __restrict__ epk,
        const float* __restrict__ dinv, const float* __restrict__ bias,
        float* __restrict__ outf, unsigned short* __restrict__ oh,
        unsigned short* __restrict__ ol) {
    constexpr int LPG = DIM / 32;   // lanes per group (each lane: uint2 = 4 cols)
    constexpr int GPW = 64 / LPG;   // groups (edges in parallel) per wave
    constexpr int U2PR = DIM / 4;   // uint2 per H row
    const int l = threadIdx.x & 63;
    const int wid = threadIdx.x >> 6;
    const int slice = blockIdx.x & 7;
    const int chunk = blockIdx.x >> 3;
    const int g = l / LPG;
    const int lg = l % LPG;
    const int t = slice * LPG + lg;  // global col-quad index (cols 4t..4t+3)
    const uint2* H2 = reinterpret_cast<const uint2*>(H);
    const long long* epk8 = reinterpret_cast<const long long*>(epk);

    for (int i = 0; i < 4; ++i) {
        int row = chunk * 16 + wid * 4 + i;
        if (row >= NN) break;  // wave-uniform
        float di = dinv[row];
        float a0 = 0.f, a1 = 0.f, a2 = 0.f, a3 = 0.f;
        int beg = rowptr[row], end = rowptr[row + 1];
        int e = beg + g;
        for (; e + GPW < end; e += 2 * GPW) {
            long long m0 = __builtin_nontemporal_load(epk8 + e);
            long long m1 = __builtin_nontemporal_load(epk8 + e + GPW);
            int s0 = (int)(unsigned)m0;
            int s1 = (int)(unsigned)m1;
            float w0 = __int_as_float((int)(m0 >> 32));
            float w1 = __int_as_float((int)(m1 >> 32));
            uint2 v0 = H2[(size_t)s0 * U2PR + t];
            uint2 v1 = H2[(size_t)s1 * U2PR + t];
            a0 += w0 * __uint_as_float(v0.x << 16);
            a1 += w0 * __uint_as_float(v0.x & 0xffff0000u);
            a2 += w0 * __uint_as_float(v0.y << 16);
            a3 += w0 * __uint_as_float(v0.y & 0xffff0000u);
            a0 += w1 * __uint_as_float(v1.x << 16);
            a1 += w1 * __uint_as_float(v1.x & 0xffff0000u);
            a2 += w1 * __uint_as_float(v1.y << 16);
            a3 += w1 * __uint_as_float(v1.y & 0xffff0000u);
        }
        if (e < end) {  // at most one leftover per group
            long long m0 = __builtin_nontemporal_load(epk8 + e);
            int s0 = (int)(unsigned)m0;
            float w0 = __int_as_float((int)(m0 >> 32));
            uint2 v0 = H2[(size_t)s0 * U2PR + t];
            a0 += w0 * __uint_as_float(v0.x << 16);
            a1 += w0 * __uint_as_float(v0.x & 0xffff0000u);
            a2 += w0 * __uint_as_float(v0.y << 16);
            a3 += w0 * __uint_as_float(v0.y & 0xffff0000u);
        }
        if (g == 0) {  // self-loop contribution
            uint2 sv = H2[(size_t)row * U2PR + t];
            a0 += di * __uint_as_float(sv.x << 16);
            a1 += di * __uint_as_float(sv.x & 0xffff0000u);
            a2 += di * __uint_as_float(sv.y << 16);
            a3 += di * __uint_as_float(sv.y & 0xffff0000u);
        }
#pragma unroll
        for (int msk = LPG; msk < 64; msk <<= 1) {
            a0 += __shfl_xor(a0, msk);
            a1 += __shfl_xor(a1, msk);
            a2 += __shfl_xor(a2, msk);
            a3 += __shfl_xor(a3, msk);
        }
        if (g == 0) {
            float4 b4 = reinterpret_cast<const float4*>(bias)[t];
            float o0 = a0 * di + b4.x;
            float o1 = a1 * di + b4.y;
            float o2 = a2 * di + b4.z;
            float o3 = a3 * di + b4.w;
            if (RELU) {
                o0 = fmaxf(o0, 0.f); o1 = fmaxf(o1, 0.f);
                o2 = fmaxf(o2, 0.f); o3 = fmaxf(o3, 0.f);
            }
            if constexpr (FRAGOUT) {
                unsigned short h0 = f2bf_u(o0), h1 = f2bf_u(o1),
                               h2 = f2bf_u(o2), h3 = f2bf_u(o3);
                u16x4 hv, lv;
                hv[0] = h0; hv[1] = h1; hv[2] = h2; hv[3] = h3;
                lv[0] = f2bf_u(o0 - bfu2f(h0));
                lv[1] = f2bf_u(o1 - bfu2f(h1));
                lv[2] = f2bf_u(o2 - bfu2f(h2));
                lv[3] = f2bf_u(o3 - bfu2f(h3));
                size_t ch = (size_t)(t >> 3) * NRBP + (row >> 4);
                int off = ((t & 7) >> 1) * 128 + (row & 15) * 8 + (t & 1) * 4;
                __builtin_nontemporal_store(hv, (u16x4*)(oh + ch * 512 + off));
                __builtin_nontemporal_store(lv, (u16x4*)(ol + ch * 512 + off));
            } else {
                f32x4 o;
                o[0] = o0; o[1] = o1; o[2] = o2; o[3] = o3;
                __builtin_nontemporal_store(o, (f32x4*)(outf) + (size_t)row * (DIM / 4) + t);
            }
        }
    }
}

// ---------------- pre-split x (fp32 [N][256]) into frag-layout hi/lo planes -------
__global__ void k_xsplit(const float* __restrict__ X, unsigned short* __restrict__ xh,
                         unsigned short* __restrict__ xl, int nrows) {
    int idx = blockIdx.x * 256 + threadIdx.x;
    int row = idx >> 6, t = idx & 63;
    if (row >= nrows) return;
    float4 v = *reinterpret_cast<const float4*>(&X[(size_t)row * 256 + t * 4]);
    ushort4 h, lo;
    h.x = f2bf_u(v.x); lo.x = f2bf_u(v.x - bfu2f(h.x));
    h.y = f2bf_u(v.y); lo.y = f2bf_u(v.y - bfu2f(h.y));
    h.z = f2bf_u(v.z); lo.z = f2bf_u(v.z - bfu2f(h.z));
    h.w = f2bf_u(v.w); lo.w = f2bf_u(v.w - bfu2f(h.w));
    size_t chunk = (size_t)(t >> 3) * NRBP + (row >> 4);
    int off = ((t & 7) >> 1) * 128 + (row & 15) * 8 + (t & 1) * 4;
    *reinterpret_cast<ushort4*>(&xh[chunk * 512 + off]) = h;
    *reinterpret_cast<ushort4*>(&xl[chunk * 512 + off]) = lo;
}

// ---------------- weight pre-split into frag-ordered hi/lo bf16 ----------------
__global__ void k_wsplit(const float* __restrict__ W, unsigned short* __restrict__ wh,
                         unsigned short* __restrict__ wl, int K, int M) {
    int idx = blockIdx.x * blockDim.x + threadIdx.x;
    if (idx >= K * M) return;
    int k = idx / M, m = idx % M;
    float w = W[idx];
    unsigned short h = f2bf_u(w);
    float hf = bfu2f(h);
    unsigned short lo = f2bf_u(w - hf);
    int kb = k >> 5, kg = (k & 31) >> 3, kj = k & 7;
    int nb = m >> 4, c = m & 15;
    int off = (kb * (M >> 4) + nb) * 512 + kg * 128 + c * 8 + kj;
    wh[off] = h;
    wl[off] = lo;
}

// ---------------- pipelined MFMA GEMM, frag-layout inputs, bf16 out -------------
template<int BM, int BN>
__global__ __launch_bounds__((BM / 64) * (BN / 64) * 64)
void k_mmf(const unsigned short* __restrict__ ah, const unsigned short* __restrict__ al,
           const unsigned short* __restrict__ wh, const unsigned short* __restrict__ wl,
           unsigned short* __restrict__ Cbf, int nrows, int K, int M) {
    constexpr int NW = (BM / 64) * (BN / 64);
    constexpr int WN = BN / 64;
    constexpr int AC = BM / 16, BC = BN / 16;
    constexpr int TC = 2 * (AC + BC);
    constexpr int BUF = TC * 512;  // shorts
    __shared__ unsigned short sm[2 * BUF];
    const int tid = threadIdx.x, l = tid & 63, wid = tid >> 6;
    const int wr = wid / WN, wc = wid % WN;
    const int bm = blockIdx.x * BM, bn = blockIdx.y * BN;
    const int rb0 = blockIdx.x * AC, nb0 = blockIdx.y * BC;
    const int NKB = K >> 5, MB = M >> 4;
    const int fo = (l >> 4) * 128 + (l & 15) * 8;
    f32x4 acc[4][4] = {};

    auto stage = [&](int buf, int kb) {
        unsigned short* base = sm + buf * BUF;
        const unsigned short* ga_h = ah + ((size_t)kb * NRBP + rb0) * 512;
        const unsigned short* ga_l = al + ((size_t)kb * NRBP + rb0) * 512;
        const unsigned short* gb_h = wh + ((size_t)kb * MB + nb0) * 512;
        const unsigned short* gb_l = wl + ((size_t)kb * MB + nb0) * 512;
        for (int q = wid; q < TC; q += NW) {
            const unsigned short* s;
            if (q < AC) s = ga_h + q * 512;
            else if (q < 2 * AC) s = ga_l + (q - AC) * 512;
            else if (q < 2 * AC + BC) s = gb_h + (q - 2 * AC) * 512;
            else s = gb_l + (q - 2 * AC - BC) * 512;
            gll16(base + q * 512, s + l * 8);
        }
    };

    stage(0, 0);
    __syncthreads();
    for (int kb = 0; kb < NKB; ++kb) {
        const int cur = kb & 1;
        if (kb + 1 < NKB) stage(cur ^ 1, kb + 1);
        const unsigned short* base = sm + cur * BUF;
        bf16x8 a_h[4], a_l[4], b_h[4], b_l[4];
#pragma unroll
        for (int i = 0; i < 4; ++i) {
            a_h[i] = *reinterpret_cast<const bf16x8*>(base + (wr * 4 + i) * 512 + fo);
            a_l[i] = *reinterpret_cast<const bf16x8*>(base + (AC + wr * 4 + i) * 512 + fo);
        }
#pragma unroll
        for (int j = 0; j < 4; ++j) {
            b_h[j] = *reinterpret_cast<const bf16x8*>(base + (2 * AC + wc * 4 + j) * 512 + fo);
            b_l[j] = *reinterpret_cast<const bf16x8*>(base + (2 * AC + BC + wc * 4 + j) * 512 + fo);
        }
#pragma unroll
        for (int i = 0; i < 4; ++i)
#pragma unroll
            for (int j = 0; j < 4; ++j) {
                acc[i][j] = __builtin_amdgcn_mfma_f32_16x16x32_bf16(a_h[i], b_h[j], acc[i][j], 0, 0, 0);
                acc[i][j] = __builtin_amdgcn_mfma_f32_16x16x32_bf16(a_h[i], b_l[j], acc[i][j], 0, 0, 0);
                acc[i][j] = __builtin_amdgcn_mfma_f32_16x16x32_bf16(a_l[i], b_h[j], acc[i][j], 0, 0, 0);
            }
        __syncthreads();
    }
#pragma unroll
    for (int j = 0; j < 4; ++j) {
        int col = bn + wc * 64 + j * 16 + (l & 15);
#pragma unroll
        for (int i = 0; i < 4; ++i) {
            int row0 = bm + wr * 64 + i * 16 + (l >> 4) * 4;
#pragma unroll
            for (int r = 0; r < 4; ++r) {
                int row = row0 + r;
                if (row < nrows)
                    Cbf[(size_t)row * M + col] = f2bf_u(acc[i][j][r]);
            }
        }
    }
}

// ---------------- head GEMM (fp32 A, in-kernel split, 3-pass) -------------------
template<int BM, int BN, bool RELU>
__global__ __launch_bounds__((BM / 64) * (BN / 64) * 64)
void k_mm(const float* __restrict__ A, const unsigned short* __restrict__ wh,
          const unsigned short* __restrict__ wl, const float* __restrict__ bias,
          float* __restrict__ Cout, int nrows, int K, int M) {
    constexpr int T = (BM / 64) * (BN / 64) * 64;
    constexpr int WN = BN / 64;
    constexpr int QI = BM * 8 / T;
    __shared__ unsigned short Ah[BM * 32], Al[BM * 32], Bh[BN * 32], Bl[BN * 32];
    int tid = threadIdx.x;
    int l = tid & 63;
    int wid = tid >> 6;
    int wr = wid / WN, wc = wid % WN;
    int bm = blockIdx.x * BM, bn = blockIdx.y * BN;
    int nb0 = bn >> 4;
    f32x4 acc[4][4] = {};
    int fo = (l >> 4) * 128 + (l & 15) * 8;

    for (int k0 = 0; k0 < K; k0 += 32) {
        int kb = k0 >> 5;
#pragma unroll
        for (int q = 0; q < QI; ++q) {
            int t2 = tid + q * T;
            int row = t2 >> 3, kq = t2 & 7;
            int grow = bm + row;
            float4 av = make_float4(0.f, 0.f, 0.f, 0.f);
            if (grow < nrows)
                av = *reinterpret_cast<const float4*>(&A[(size_t)grow * K + k0 + kq * 4]);
            unsigned short h0 = f2bf_u(av.x), h1 = f2bf_u(av.y),
                           h2 = f2bf_u(av.z), h3 = f2bf_u(av.w);
            uint2 hp, lp;
            hp.x = (unsigned)h0 | ((unsigned)h1 << 16);
            hp.y = (unsigned)h2 | ((unsigned)h3 << 16);
            lp.x = (unsigned)f2bf_u(av.x - bfu2f(h0)) | ((unsigned)f2bf_u(av.y - bfu2f(h1)) << 16);
            lp.y = (unsigned)f2bf_u(av.z - bfu2f(h2)) | ((unsigned)f2bf_u(av.w - bfu2f(h3)) << 16);
            int off = (row >> 4) * 512 + (kq >> 1) * 128 + (row & 15) * 8 + (kq & 1) * 4;
            *reinterpret_cast<uint2*>(&Ah[off]) = hp;
            *reinterpret_cast<uint2*>(&Al[off]) = lp;
        }
        const int4* sh = reinterpret_cast<const int4*>(wh) + (size_t)(kb * (M >> 4) + nb0) * 64;
        const int4* sl = reinterpret_cast<const int4*>(wl) + (size_t)(kb * (M >> 4) + nb0) * 64;
        for (int u = tid; u < BN * 4; u += T) {
            *reinterpret_cast<int4*>(&Bh[u * 8]) = sh[u];
            *reinterpret_cast<int4*>(&Bl[u * 8]) = sl[u];
        }
        __syncthreads();
        bf16x8 ah4[4], al4[4], bh4[4], bl4[4];
#pragma unroll
        for (int i = 0; i < 4; ++i) {
            ah4[i] = *reinterpret_cast<const bf16x8*>(&Ah[(wr * 4 + i) * 512 + fo]);
            al4[i] = *reinterpret_cast<const bf16x8*>(&Al[(wr * 4 + i) * 512 + fo]);
        }
#pragma unroll
        for (int j = 0; j < 4; ++j) {
            bh4[j] = *reinterpret_cast<const bf16x8*>(&Bh[(wc * 4 + j) * 512 + fo]);
            bl4[j] = *reinterpret_cast<const bf16x8*>(&Bl[(wc * 4 + j) * 512 + fo]);
        }
#pragma unroll
        for (int i = 0; i < 4; ++i)
#pragma unroll
            for (int j = 0; j < 4; ++j) {
                acc[i][j] = __builtin_amdgcn_mfma_f32_16x16x32_bf16(ah4[i], bh4[j], acc[i][j], 0, 0, 0);
                acc[i][j] = __builtin_amdgcn_mfma_f32_16x16x32_bf16(ah4[i], bl4[j], acc[i][j], 0, 0, 0);
                acc[i][j] = __builtin_amdgcn_mfma_f32_16x16x32_bf16(al4[i], bh4[j], acc[i][j], 0, 0, 0);
            }
        __syncthreads();
    }
#pragma unroll
    for (int j = 0; j < 4; ++j) {
        int col = bn + wc * 64 + j * 16 + (l & 15);
        float bv = bias[col];
#pragma unroll
        for (int i = 0; i < 4; ++i) {
            int row0 = bm + wr * 64 + i * 16 + (l >> 4) * 4;
#pragma unroll
            for (int r = 0; r < 4; ++r) {
                int row = row0 + r;
                if (row < nrows) {
                    float v = acc[i][j][r] + bv;
                    if (RELU) v = fmaxf(v, 0.f);
                    Cout[(size_t)row * M + col] = v;
                }
            }
        }
    }
}

// ---------------- launch ----------------

extern "C" void kernel_launch(void* const* d_in, const int* in_sizes, int n_in,
                              void* d_out, int out_size, void* d_ws, size_t ws_size,
                              hipStream_t stream) {
    const float* x        = (const float*)d_in[0];
    const int*   edge_row = (const int*)d_in[1];
    const int*   edge_col = (const int*)d_in[2];
    const float* edge_val = (const float*)d_in[3];
    const float* W1  = (const float*)d_in[4];
    const float* b1  = (const float*)d_in[5];
    const float* W2  = (const float*)d_in[6];
    const float* b2  = (const float*)d_in[7];
    const float* W3  = (const float*)d_in[8];
    const float* b3  = (const float*)d_in[9];
    const float* P1  = (const float*)d_in[10];
    const float* pb1 = (const float*)d_in[11];
    const float* P2  = (const float*)d_in[12];
    const float* pb2 = (const float*)d_in[13];

    const int N = NN, E = NE;

    uintptr_t p = (uintptr_t)d_ws;
    auto alloc = [&](size_t bytes) -> void* {
        void* r = (void*)p;
        p += (bytes + 255) & ~(size_t)255;
        return r;
    };
    float* dinv   = (float*)alloc((size_t)N * 4);
    int*   rowptr = (int*)alloc((size_t)(N + 1) * 4);
    int*   bcnt   = (int*)alloc(256 * 4);
    int*   boff   = (int*)alloc(256 * 4);
    int*   gcur   = (int*)alloc(256 * 4);
    int2*  etmp   = (int2*)alloc((size_t)E * 8);
    int2*  epk    = (int2*)alloc((size_t)E * 8);
    unsigned short* Hbf = (unsigned short*)alloc((size_t)N * 256 * 2);
    const size_t PLANE = (size_t)8 * NRBP * 512 * 2;  // bytes
    unsigned short* pAh = (unsigned short*)alloc(PLANE);
    unsigned short* pAl = (unsigned short*)alloc(PLANE);
    unsigned short* pBh = (unsigned short*)alloc(PLANE);
    unsigned short* pBl = (unsigned short*)alloc(PLANE);
    float* bufT = (float*)pBh;  // head intermediate aliases pBh (free after GEMM3)
    unsigned short* wf1h = (unsigned short*)alloc(65536 * 2);
    unsigned short* wf1l = (unsigned short*)alloc(65536 * 2);
    unsigned short* wf2h = (unsigned short*)alloc(65536 * 2);
    unsigned short* wf2l = (unsigned short*)alloc(65536 * 2);
    unsigned short* wf3h = (unsigned short*)alloc(32768 * 2);
    unsigned short* wf3l = (unsigned short*)alloc(32768 * 2);
    unsigned short* p1h  = (unsigned short*)alloc(16384 * 2);
    unsigned short* p1l  = (unsigned short*)alloc(16384 * 2);
    unsigned short* p2h  = (unsigned short*)alloc(16384 * 2);
    unsigned short* p2l  = (unsigned short*)alloc(16384 * 2);

    float* emb = (float*)d_out;
    float* z   = (float*)d_out + (size_t)N * 128;

    dim3 b256(256);
    const int gE1k = (E + 1023) / 1024;  // 782

    // weight/x splits (independent)
    k_wsplit<<<dim3(256), b256, 0, stream>>>(W1, wf1h, wf1l, 256, 256);
    k_wsplit<<<dim3(256), b256, 0, stream>>>(W2, wf2h, wf2l, 256, 256);
    k_wsplit<<<dim3(128), b256, 0, stream>>>(W3, wf3h, wf3l, 256, 128);
    k_wsplit<<<dim3(64),  b256, 0, stream>>>(P1, p1h, p1l, 128, 128);
    k_wsplit<<<dim3(64),  b256, 0, stream>>>(P2, p2h, p2l, 128, 128);
    k_xsplit<<<dim3((N * 64 + 255) / 256), b256, 0, stream>>>(x, pAh, pAl, N);

    // CSR build: bucket histogram -> scan -> bucket scatter -> in-bucket sort(+deg)
    hipMemsetAsync(bcnt, 0, 256 * 4, stream);
    k_bhist<<<dim3(gE1k), b256, 0, stream>>>(edge_col, bcnt, E);
    k_bscan<<<dim3(1), b256, 0, stream>>>(bcnt, boff, gcur, rowptr);
    k_bscat<<<dim3(gE1k), b256, 0, stream>>>(edge_row, edge_col, edge_val, gcur, etmp, E);
    k_bsort<<<dim3(NBK), b256, 0, stream>>>(etmp, boff, rowptr, dinv, epk);
    k_normw<<<dim3((E + 255) / 256), b256, 0, stream>>>(epk, dinv, E);

    const int gaggs = 8 * ((N + 15) / 16);  // 8 slices x 3125 row-chunks = 25000

    // layer 1: Hbf = x @ W1 ; pB = split(relu(agg(Hbf)*dinv + b1))
    k_mmf<128, 128><<<dim3(391, 2), dim3(256), 0, stream>>>(pAh, pAl, wf1h, wf1l, Hbf, N, 256, 256);
    k_aggs<256, true, true><<<dim3(gaggs), b256, 0, stream>>>(Hbf, rowptr, epk, dinv, b1, nullptr, pBh, pBl);
    // layer 2
    k_mmf<128, 128><<<dim3(391, 2), dim3(256), 0, stream>>>(pBh, pBl, wf2h, wf2l, Hbf, N, 256, 256);
    k_aggs<256, true, true><<<dim3(gaggs), b256, 0, stream>>>(Hbf, rowptr, epk, dinv, b2, nullptr, pAh, pAl);
    // layer 3
    k_mmf<64, 128><<<dim3(782, 1), dim3(128), 0, stream>>>(pAh, pAl, wf3h, wf3l, Hbf, N, 256, 128);
    k_aggs<128, false, false><<<dim3(gaggs), b256, 0, stream>>>(Hbf, rowptr, epk, dinv, b3, emb, nullptr, nullptr);
    // head: z = relu(emb @ P1 + pb1) @ P2 + pb2
    k_mm<64, 128, true ><<<dim3(782, 1), dim3(128), 0, stream>>>(emb, p1h, p1l, pb1, bufT, N, 128, 128);
    k_mm<64, 128, false><<<dim3(782, 1), dim3(128), 0, stream>>>(bufT, p2h, p2l, pb2, z, N, 128, 128);
}

// Round 9
// 374.000 us; speedup vs baseline: 2.4970x; 2.4970x over previous
//
#include <hip/hip_runtime.h>
#include <hip/hip_bf16.h>
#include <cstdint>
#include <cstddef>

#define NN 50000
#define NE 800000
#define NRBP 3128  // padded row-chunk count: ceil(50000/16)=3125 -> pad to mult of 8
#define NBK 196    // coarse buckets: dest >> 8  (50000/256 -> 196)

typedef __attribute__((ext_vector_type(8))) short bf16x8;
typedef __attribute__((ext_vector_type(4))) float f32x4;

static __device__ __forceinline__ unsigned short f2bf_u(float f) {
    __hip_bfloat16 h = __float2bfloat16(f);
    return *reinterpret_cast<unsigned short*>(&h);
}
static __device__ __forceinline__ float bfu2f(unsigned short u) {
    __hip_bfloat16 h = *reinterpret_cast<__hip_bfloat16*>(&u);
    return __bfloat162float(h);
}

// async global->LDS, 16B per lane. lds dst must be wave-uniform (HW adds lane*16).
static __device__ __forceinline__ void gll16(void* lds_dst, const void* gsrc) {
    __builtin_amdgcn_global_load_lds(
        (const __attribute__((address_space(1))) void*)gsrc,
        (__attribute__((address_space(3))) void*)lds_dst, 16, 0, 0);
}

// ================= CSR build: bucket sort (LDS-localized, low atomic thrash) ====

__global__ __launch_bounds__(256) void k_bhist(const int* __restrict__ ecol,
                                               int* __restrict__ bcnt, int e) {
    __shared__ int lcnt[NBK];
    int tid = threadIdx.x;
    for (int t = tid; t < NBK; t += 256) lcnt[t] = 0;
    __syncthreads();
#pragma unroll
    for (int q = 0; q < 4; ++q) {
        int i = blockIdx.x * 1024 + q * 256 + tid;
        if (i < e) atomicAdd(&lcnt[ecol[i] >> 8], 1);
    }
    __syncthreads();
    for (int t = tid; t < NBK; t += 256)
        if (lcnt[t]) atomicAdd(&bcnt[t], lcnt[t]);
}

__global__ void k_bscan(const int* __restrict__ bcnt, int* __restrict__ boff,
                        int* __restrict__ gcur, int* __restrict__ rowptr) {
    int tid = threadIdx.x;
    int v = (tid < NBK) ? bcnt[tid] : 0;
    int lane = tid & 63, w = tid >> 6;
    int incl = v;
#pragma unroll
    for (int d = 1; d < 64; d <<= 1) {
        int t = __shfl_up(incl, d);
        if (lane >= d) incl += t;
    }
    __shared__ int wsum[4];
    if (lane == 63) wsum[w] = incl;
    __syncthreads();
    int woff = 0;
    for (int j = 0; j < w; ++j) woff += wsum[j];
    int ex = woff + incl - v;
    if (tid < NBK) { boff[tid] = ex; gcur[tid] = ex; }
    if (tid == 255) { boff[NBK] = ex; rowptr[NN] = ex; }  // == E
}

__global__ __launch_bounds__(256) void k_bscat(const int* __restrict__ erow,
                                               const int* __restrict__ ecol,
                                               const float* __restrict__ eval_,
                                               int* __restrict__ gcur,
                                               int2* __restrict__ tmp, int e) {
    __shared__ int lcnt[NBK], lbase[NBK], lcur[NBK];
    int tid = threadIdx.x;
    for (int t = tid; t < NBK; t += 256) { lcnt[t] = 0; lcur[t] = 0; }
    __syncthreads();
    int d_[4], b_[4];
#pragma unroll
    for (int q = 0; q < 4; ++q) {
        int i = blockIdx.x * 1024 + q * 256 + tid;
        d_[q] = -1;
        if (i < e) {
            d_[q] = ecol[i];
            b_[q] = d_[q] >> 8;
            atomicAdd(&lcnt[b_[q]], 1);
        }
    }
    __syncthreads();
    for (int t = tid; t < NBK; t += 256)
        lbase[t] = lcnt[t] ? atomicAdd(&gcur[t], lcnt[t]) : 0;
    __syncthreads();
#pragma unroll
    for (int q = 0; q < 4; ++q) {
        int i = blockIdx.x * 1024 + q * 256 + tid;
        if (i < e) {
            int b = b_[q];
            int pos = lbase[b] + atomicAdd(&lcur[b], 1);
            tmp[pos] = make_int2(erow[i] | ((d_[q] & 255) << 20), __float_as_int(eval_[i]));
        }
    }
}

__global__ __launch_bounds__(256) void k_bsort(const int2* __restrict__ tmp,
                                               const int* __restrict__ boff,
                                               int* __restrict__ rowptr,
                                               float* __restrict__ dinv,
                                               int2* __restrict__ epk) {
    __shared__ int lcnt[256], lcur[256];
    __shared__ float ldeg[256];
    __shared__ int wsum[4];
    int tid = threadIdx.x;
    int b = blockIdx.x;
    int base = boff[b], endb = boff[b + 1];
    lcnt[tid] = 0;
    ldeg[tid] = 0.f;
    __syncthreads();
    for (int i = base + tid; i < endb; i += 256) {
        int2 e2 = tmp[i];
        int d = e2.x >> 20;
        atomicAdd(&lcnt[d], 1);
        atomicAdd(&ldeg[d], __int_as_float(e2.y));
    }
    __syncthreads();
    int v = lcnt[tid];
    int lane = tid & 63, w = tid >> 6;
    int incl = v;
#pragma unroll
    for (int d = 1; d < 64; d <<= 1) {
        int t = __shfl_up(incl, d);
        if (lane >= d) incl += t;
    }
    if (lane == 63) wsum[w] = incl;
    __syncthreads();
    int woff = 0;
    for (int j = 0; j < w; ++j) woff += wsum[j];
    int ex = woff + incl - v;
    int dest = (b << 8) + tid;
    if (dest < NN) {
        rowptr[dest] = base + ex;
        dinv[dest] = rsqrtf(1.f + ldeg[tid]);
    }
    lcur[tid] = ex;
    __syncthreads();
    for (int i = base + tid; i < endb; i += 256) {
        int2 e2 = tmp[i];
        int d = e2.x >> 20;
        int pos = base + atomicAdd(&lcur[d], 1);
        epk[pos] = make_int2(e2.x & 0xFFFFF, e2.y);
    }
}

// epk.y := raw_val * dinv[src]  (dst factor applied in agg)
__global__ void k_normw(int2* __restrict__ epk, const float* __restrict__ dinv, int e) {
    int i = blockIdx.x * 256 + threadIdx.x;
    if (i < e) {
        int2 pk = epk[i];
        epk[i].y = __float_as_int(__int_as_float(pk.y) * dinv[pk.x]);
    }
}

// ---------------- sparse aggregation: wave-per-row, shfl indices (round-6) ------
// out[i,:] = dinv_i * ( dinv_i*H[i,:] + sum_e w'_e * H[src_e,:] ) + bias  (opt relu)
// FRAGOUT: write bf16 (hi only) in GEMM A-fragment layout instead of fp32.
template<int DIM, bool RELU, bool FRAGOUT>
__global__ __launch_bounds__(256) void k_agg(const unsigned short* __restrict__ H,
                      const int* __restrict__ rowptr, const int2* __restrict__ epk,
                      const float* __restrict__ dinv, const float* __restrict__ bias,
                      float* __restrict__ outf, unsigned short* __restrict__ oh) {
    constexpr int WU = DIM / 128;  // uints per lane
    int lane = threadIdx.x & 63;
    int row = blockIdx.x * 4 + (threadIdx.x >> 6);
    if (row >= NN) return;

    const uint2* H2 = reinterpret_cast<const uint2*>(H);
    const unsigned* H1 = reinterpret_cast<const unsigned*>(H);

    auto loadrow = [&](int r, unsigned* v) {
        if constexpr (WU == 2) {
            uint2 t = H2[(size_t)r * 64 + lane];
            v[0] = t.x; v[1] = t.y;
        } else {
            v[0] = H1[(size_t)r * 64 + lane];
        }
    };

    float di = dinv[row];
    float acc[WU * 2];
    {
        unsigned sv[WU];
        loadrow(row, sv);
#pragma unroll
        for (int w2 = 0; w2 < WU; ++w2) {
            acc[w2 * 2 + 0] = di * __uint_as_float(sv[w2] << 16);
            acc[w2 * 2 + 1] = di * __uint_as_float(sv[w2] & 0xffff0000u);
        }
    }

    auto accum = [&](const unsigned* v, float wt) {
#pragma unroll
        for (int w2 = 0; w2 < WU; ++w2) {
            acc[w2 * 2 + 0] += wt * __uint_as_float(v[w2] << 16);
            acc[w2 * 2 + 1] += wt * __uint_as_float(v[w2] & 0xffff0000u);
        }
    };

    int beg = rowptr[row], end = rowptr[row + 1];
    for (int c = beg; c < end; c += 64) {
        int m = min(64, end - c);
        int2 pk = make_int2(0, 0);
        if (c + lane < end) pk = epk[c + lane];
        int j = 0;
        for (; j + 4 <= m; j += 4) {
            int s0 = __shfl(pk.x, j + 0), s1 = __shfl(pk.x, j + 1);
            int s2 = __shfl(pk.x, j + 2), s3 = __shfl(pk.x, j + 3);
            float w0 = __int_as_float(__shfl(pk.y, j + 0));
            float w1 = __int_as_float(__shfl(pk.y, j + 1));
            float w2 = __int_as_float(__shfl(pk.y, j + 2));
            float w3 = __int_as_float(__shfl(pk.y, j + 3));
            unsigned g0[WU], g1[WU], g2[WU], g3[WU];
            loadrow(s0, g0);
            loadrow(s1, g1);
            loadrow(s2, g2);
            loadrow(s3, g3);
            accum(g0, w0);
            accum(g1, w1);
            accum(g2, w2);
            accum(g3, w3);
        }
        for (; j < m; ++j) {
            int s = __shfl(pk.x, j);
            float wt = __int_as_float(__shfl(pk.y, j));
            unsigned g[WU];
            loadrow(s, g);
            accum(g, wt);
        }
    }

    if constexpr (FRAGOUT) {
        // DIM==256: cols 4*lane..4*lane+3
        float4 b4 = reinterpret_cast<const float4*>(bias)[lane];
        float o0 = acc[0] * di + b4.x;
        float o1 = acc[1] * di + b4.y;
        float o2 = acc[2] * di + b4.z;
        float o3 = acc[3] * di + b4.w;
        if (RELU) {
            o0 = fmaxf(o0, 0.f); o1 = fmaxf(o1, 0.f);
            o2 = fmaxf(o2, 0.f); o3 = fmaxf(o3, 0.f);
        }
        ushort4 h;
        h.x = f2bf_u(o0); h.y = f2bf_u(o1); h.z = f2bf_u(o2); h.w = f2bf_u(o3);
        size_t ch = (size_t)(lane >> 3) * NRBP + (row >> 4);
        int off = ((lane & 7) >> 1) * 128 + (row & 15) * 8 + (lane & 1) * 4;
        *reinterpret_cast<ushort4*>(&oh[ch * 512 + off]) = h;
    } else if constexpr (WU == 2) {
        float4 b4 = reinterpret_cast<const float4*>(bias)[lane];
        float4 o;
        o.x = acc[0] * di + b4.x; o.y = acc[1] * di + b4.y;
        o.z = acc[2] * di + b4.z; o.w = acc[3] * di + b4.w;
        if (RELU) {
            o.x = fmaxf(o.x, 0.f); o.y = fmaxf(o.y, 0.f);
            o.z = fmaxf(o.z, 0.f); o.w = fmaxf(o.w, 0.f);
        }
        reinterpret_cast<float4*>(outf)[(size_t)row * 64 + lane] = o;
    } else {
        float2 b2 = reinterpret_cast<const float2*>(bias)[lane];
        float2 o;
        o.x = acc[0] * di + b2.x; o.y = acc[1] * di + b2.y;
        if (RELU) { o.x = fmaxf(o.x, 0.f); o.y = fmaxf(o.y, 0.f); }
        reinterpret_cast<float2*>(outf)[(size_t)row * 64 + lane] = o;
    }
}

// ---------------- pre-split x (fp32 [N][256]) into frag-layout bf16 (hi only) ----
__global__ void k_xsplit(const float* __restrict__ X, unsigned short* __restrict__ xh,
                         int nrows) {
    int idx = blockIdx.x * 256 + threadIdx.x;
    int row = idx >> 6, t = idx & 63;
    if (row >= nrows) return;
    float4 v = *reinterpret_cast<const float4*>(&X[(size_t)row * 256 + t * 4]);
    ushort4 h;
    h.x = f2bf_u(v.x); h.y = f2bf_u(v.y); h.z = f2bf_u(v.z); h.w = f2bf_u(v.w);
    size_t chunk = (size_t)(t >> 3) * NRBP + (row >> 4);
    int off = ((t & 7) >> 1) * 128 + (row & 15) * 8 + (t & 1) * 4;
    *reinterpret_cast<ushort4*>(&xh[chunk * 512 + off]) = h;
}

// ---------------- weight pre-split into frag-ordered hi/lo bf16 ----------------
__global__ void k_wsplit(const float* __restrict__ W, unsigned short* __restrict__ wh,
                         unsigned short* __restrict__ wl, int K, int M) {
    int idx = blockIdx.x * blockDim.x + threadIdx.x;
    if (idx >= K * M) return;
    int k = idx / M, m = idx % M;
    float w = W[idx];
    unsigned short h = f2bf_u(w);
    float hf = bfu2f(h);
    unsigned short lo = f2bf_u(w - hf);
    int kb = k >> 5, kg = (k & 31) >> 3, kj = k & 7;
    int nb = m >> 4, c = m & 15;
    int off = (kb * (M >> 4) + nb) * 512 + kg * 128 + c * 8 + kj;
    wh[off] = h;
    wl[off] = lo;
}

// ----- pipelined MFMA GEMM: A = bf16 frag planes (hi only), W = hi/lo, 2-pass ----
template<int BM, int BN>
__global__ __launch_bounds__((BM / 64) * (BN / 64) * 64)
void k_mmf(const unsigned short* __restrict__ ah,
           const unsigned short* __restrict__ wh, const unsigned short* __restrict__ wl,
           unsigned short* __restrict__ Cbf, int nrows, int K, int M) {
    constexpr int NW = (BM / 64) * (BN / 64);
    constexpr int WN = BN / 64;
    constexpr int AC = BM / 16, BC = BN / 16;
    constexpr int TC = AC + 2 * BC;
    constexpr int BUF = TC * 512;  // shorts
    __shared__ unsigned short sm[2 * BUF];
    const int tid = threadIdx.x, l = tid & 63, wid = tid >> 6;
    const int wr = wid / WN, wc = wid % WN;
    const int bm = blockIdx.x * BM, bn = blockIdx.y * BN;
    const int rb0 = blockIdx.x * AC, nb0 = blockIdx.y * BC;
    const int NKB = K >> 5, MB = M >> 4;
    const int fo = (l >> 4) * 128 + (l & 15) * 8;
    f32x4 acc[4][4] = {};

    auto stage = [&](int buf, int kb) {
        unsigned short* base = sm + buf * BUF;
        const unsigned short* ga_h = ah + ((size_t)kb * NRBP + rb0) * 512;
        const unsigned short* gb_h = wh + ((size_t)kb * MB + nb0) * 512;
        const unsigned short* gb_l = wl + ((size_t)kb * MB + nb0) * 512;
        for (int q = wid; q < TC; q += NW) {
            const unsigned short* s;
            if (q < AC) s = ga_h + q * 512;
            else if (q < AC + BC) s = gb_h + (q - AC) * 512;
            else s = gb_l + (q - AC - BC) * 512;
            gll16(base + q * 512, s + l * 8);
        }
    };

    stage(0, 0);
    __syncthreads();
    for (int kb = 0; kb < NKB; ++kb) {
        const int cur = kb & 1;
        if (kb + 1 < NKB) stage(cur ^ 1, kb + 1);
        const unsigned short* base = sm + cur * BUF;
        bf16x8 a_h[4], b_h[4], b_l[4];
#pragma unroll
        for (int i = 0; i < 4; ++i)
            a_h[i] = *reinterpret_cast<const bf16x8*>(base + (wr * 4 + i) * 512 + fo);
#pragma unroll
        for (int j = 0; j < 4; ++j) {
            b_h[j] = *reinterpret_cast<const bf16x8*>(base + (AC + wc * 4 + j) * 512 + fo);
            b_l[j] = *reinterpret_cast<const bf16x8*>(base + (AC + BC + wc * 4 + j) * 512 + fo);
        }
#pragma unroll
        for (int i = 0; i < 4; ++i)
#pragma unroll
            for (int j = 0; j < 4; ++j) {
                acc[i][j] = __builtin_amdgcn_mfma_f32_16x16x32_bf16(a_h[i], b_h[j], acc[i][j], 0, 0, 0);
                acc[i][j] = __builtin_amdgcn_mfma_f32_16x16x32_bf16(a_h[i], b_l[j], acc[i][j], 0, 0, 0);
            }
        __syncthreads();
    }
#pragma unroll
    for (int j = 0; j < 4; ++j) {
        int col = bn + wc * 64 + j * 16 + (l & 15);
#pragma unroll
        for (int i = 0; i < 4; ++i) {
            int row0 = bm + wr * 64 + i * 16 + (l >> 4) * 4;
#pragma unroll
            for (int r = 0; r < 4; ++r) {
                int row = row0 + r;
                if (row < nrows)
                    Cbf[(size_t)row * M + col] = f2bf_u(acc[i][j][r]);
            }
        }
    }
}

// ---------------- head GEMM (fp32 A, in-kernel split, 3-pass) -------------------
template<int BM, int BN, bool RELU>
__global__ __launch_bounds__((BM / 64) * (BN / 64) * 64)
void k_mm(const float* __restrict__ A, const unsigned short* __restrict__ wh,
          const unsigned short* __restrict__ wl, const float* __restrict__ bias,
          float* __restrict__ Cout, int nrows, int K, int M) {
    constexpr int T = (BM / 64) * (BN / 64) * 64;
    constexpr int WN = BN / 64;
    constexpr int QI = BM * 8 / T;
    __shared__ unsigned short Ah[BM * 32], Al[BM * 32], Bh[BN * 32], Bl[BN * 32];
    int tid = threadIdx.x;
    int l = tid & 63;
    int wid = tid >> 6;
    int wr = wid / WN, wc = wid % WN;
    int bm = blockIdx.x * BM, bn = blockIdx.y * BN;
    int nb0 = bn >> 4;
    f32x4 acc[4][4] = {};
    int fo = (l >> 4) * 128 + (l & 15) * 8;

    for (int k0 = 0; k0 < K; k0 += 32) {
        int kb = k0 >> 5;
#pragma unroll
        for (int q = 0; q < QI; ++q) {
            int t2 = tid + q * T;
            int row = t2 >> 3, kq = t2 & 7;
            int grow = bm + row;
            float4 av = make_float4(0.f, 0.f, 0.f, 0.f);
            if (grow < nrows)
                av = *reinterpret_cast<const float4*>(&A[(size_t)grow * K + k0 + kq * 4]);
            unsigned short h0 = f2bf_u(av.x), h1 = f2bf_u(av.y),
                           h2 = f2bf_u(av.z), h3 = f2bf_u(av.w);
            uint2 hp, lp;
            hp.x = (unsigned)h0 | ((unsigned)h1 << 16);
            hp.y = (unsigned)h2 | ((unsigned)h3 << 16);
            lp.x = (unsigned)f2bf_u(av.x - bfu2f(h0)) | ((unsigned)f2bf_u(av.y - bfu2f(h1)) << 16);
            lp.y = (unsigned)f2bf_u(av.z - bfu2f(h2)) | ((unsigned)f2bf_u(av.w - bfu2f(h3)) << 16);
            int off = (row >> 4) * 512 + (kq >> 1) * 128 + (row & 15) * 8 + (kq & 1) * 4;
            *reinterpret_cast<uint2*>(&Ah[off]) = hp;
            *reinterpret_cast<uint2*>(&Al[off]) = lp;
        }
        const int4* sh = reinterpret_cast<const int4*>(wh) + (size_t)(kb * (M >> 4) + nb0) * 64;
        const int4* sl = reinterpret_cast<const int4*>(wl) + (size_t)(kb * (M >> 4) + nb0) * 64;
        for (int u = tid; u < BN * 4; u += T) {
            *reinterpret_cast<int4*>(&Bh[u * 8]) = sh[u];
            *reinterpret_cast<int4*>(&Bl[u * 8]) = sl[u];
        }
        __syncthreads();
        bf16x8 ah4[4], al4[4], bh4[4], bl4[4];
#pragma unroll
        for (int i = 0; i < 4; ++i) {
            ah4[i] = *reinterpret_cast<const bf16x8*>(&Ah[(wr * 4 + i) * 512 + fo]);
            al4[i] = *reinterpret_cast<const bf16x8*>(&Al[(wr * 4 + i) * 512 + fo]);
        }
#pragma unroll
        for (int j = 0; j < 4; ++j) {
            bh4[j] = *reinterpret_cast<const bf16x8*>(&Bh[(wc * 4 + j) * 512 + fo]);
            bl4[j] = *reinterpret_cast<const bf16x8*>(&Bl[(wc * 4 + j) * 512 + fo]);
        }
#pragma unroll
        for (int i = 0; i < 4; ++i)
#pragma unroll
            for (int j = 0; j < 4; ++j) {
                acc[i][j] = __builtin_amdgcn_mfma_f32_16x16x32_bf16(ah4[i], bh4[j], acc[i][j], 0, 0, 0);
                acc[i][j] = __builtin_amdgcn_mfma_f32_16x16x32_bf16(ah4[i], bl4[j], acc[i][j], 0, 0, 0);
                acc[i][j] = __builtin_amdgcn_mfma_f32_16x16x32_bf16(al4[i], bh4[j], acc[i][j], 0, 0, 0);
            }
        __syncthreads();
    }
#pragma unroll
    for (int j = 0; j < 4; ++j) {
        int col = bn + wc * 64 + j * 16 + (l & 15);
        float bv = bias[col];
#pragma unroll
        for (int i = 0; i < 4; ++i) {
            int row0 = bm + wr * 64 + i * 16 + (l >> 4) * 4;
#pragma unroll
            for (int r = 0; r < 4; ++r) {
                int row = row0 + r;
                if (row < nrows) {
                    float v = acc[i][j][r] + bv;
                    if (RELU) v = fmaxf(v, 0.f);
                    Cout[(size_t)row * M + col] = v;
                }
            }
        }
    }
}

// ---------------- launch ----------------

extern "C" void kernel_launch(void* const* d_in, const int* in_sizes, int n_in,
                              void* d_out, int out_size, void* d_ws, size_t ws_size,
                              hipStream_t stream) {
    const float* x        = (const float*)d_in[0];
    const int*   edge_row = (const int*)d_in[1];
    const int*   edge_col = (const int*)d_in[2];
    const float* edge_val = (const float*)d_in[3];
    const float* W1  = (const float*)d_in[4];
    const float* b1  = (const float*)d_in[5];
    const float* W2  = (const float*)d_in[6];
    const float* b2  = (const float*)d_in[7];
    const float* W3  = (const float*)d_in[8];
    const float* b3  = (const float*)d_in[9];
    const float* P1  = (const float*)d_in[10];
    const float* pb1 = (const float*)d_in[11];
    const float* P2  = (const float*)d_in[12];
    const float* pb2 = (const float*)d_in[13];

    const int N = NN, E = NE;

    uintptr_t p = (uintptr_t)d_ws;
    auto alloc = [&](size_t bytes) -> void* {
        void* r = (void*)p;
        p += (bytes + 255) & ~(size_t)255;
        return r;
    };
    float* dinv   = (float*)alloc((size_t)N * 4);
    int*   rowptr = (int*)alloc((size_t)(N + 1) * 4);
    int*   bcnt   = (int*)alloc(256 * 4);
    int*   boff   = (int*)alloc(256 * 4);
    int*   gcur   = (int*)alloc(256 * 4);
    int2*  etmp   = (int2*)alloc((size_t)E * 8);
    int2*  epk    = (int2*)alloc((size_t)E * 8);
    unsigned short* Hbf = (unsigned short*)alloc((size_t)N * 256 * 2);
    const size_t PLANE = (size_t)8 * NRBP * 512 * 2;  // bytes
    unsigned short* pAh = (unsigned short*)alloc(PLANE);
    unsigned short* pBh = (unsigned short*)alloc(PLANE);
    float* bufT = (float*)alloc((size_t)N * 128 * 4);  // head intermediate
    unsigned short* wf1h = (unsigned short*)alloc(65536 * 2);
    unsigned short* wf1l = (unsigned short*)alloc(65536 * 2);
    unsigned short* wf2h = (unsigned short*)alloc(65536 * 2);
    unsigned short* wf2l = (unsigned short*)alloc(65536 * 2);
    unsigned short* wf3h = (unsigned short*)alloc(32768 * 2);
    unsigned short* wf3l = (unsigned short*)alloc(32768 * 2);
    unsigned short* p1h  = (unsigned short*)alloc(16384 * 2);
    unsigned short* p1l  = (unsigned short*)alloc(16384 * 2);
    unsigned short* p2h  = (unsigned short*)alloc(16384 * 2);
    unsigned short* p2l  = (unsigned short*)alloc(16384 * 2);

    float* emb = (float*)d_out;
    float* z   = (float*)d_out + (size_t)N * 128;

    dim3 b256(256);
    const int gE1k = (E + 1023) / 1024;  // 782

    // weight/x splits (independent)
    k_wsplit<<<dim3(256), b256, 0, stream>>>(W1, wf1h, wf1l, 256, 256);
    k_wsplit<<<dim3(256), b256, 0, stream>>>(W2, wf2h, wf2l, 256, 256);
    k_wsplit<<<dim3(128), b256, 0, stream>>>(W3, wf3h, wf3l, 256, 128);
    k_wsplit<<<dim3(64),  b256, 0, stream>>>(P1, p1h, p1l, 128, 128);
    k_wsplit<<<dim3(64),  b256, 0, stream>>>(P2, p2h, p2l, 128, 128);
    k_xsplit<<<dim3((N * 64 + 255) / 256), b256, 0, stream>>>(x, pAh, N);

    // CSR build: bucket histogram -> scan -> bucket scatter -> in-bucket sort(+deg)
    hipMemsetAsync(bcnt, 0, 256 * 4, stream);
    k_bhist<<<dim3(gE1k), b256, 0, stream>>>(edge_col, bcnt, E);
    k_bscan<<<dim3(1), b256, 0, stream>>>(bcnt, boff, gcur, rowptr);
    k_bscat<<<dim3(gE1k), b256, 0, stream>>>(edge_row, edge_col, edge_val, gcur, etmp, E);
    k_bsort<<<dim3(NBK), b256, 0, stream>>>(etmp, boff, rowptr, dinv, epk);
    k_normw<<<dim3((E + 255) / 256), b256, 0, stream>>>(epk, dinv, E);

    const int gagg = (N + 3) / 4;  // 12500

    // layer 1: Hbf = x @ W1 ; pBh = bf16(relu(agg(Hbf)*dinv + b1)) in frag layout
    k_mmf<128, 128><<<dim3(391, 2), dim3(256), 0, stream>>>(pAh, wf1h, wf1l, Hbf, N, 256, 256);
    k_agg<256, true, true><<<dim3(gagg), b256, 0, stream>>>(Hbf, rowptr, epk, dinv, b1, nullptr, pBh);
    // layer 2
    k_mmf<128, 128><<<dim3(391, 2), dim3(256), 0, stream>>>(pBh, wf2h, wf2l, Hbf, N, 256, 256);
    k_agg<256, true, true><<<dim3(gagg), b256, 0, stream>>>(Hbf, rowptr, epk, dinv, b2, nullptr, pAh);
    // layer 3
    k_mmf<64, 128><<<dim3(782, 1), dim3(128), 0, stream>>>(pAh, wf3h, wf3l, Hbf, N, 256, 128);
    k_agg<128, false, false><<<dim3(gagg), b256, 0, stream>>>(Hbf, rowptr, epk, dinv, b3, emb, nullptr);
    // head: z = relu(emb @ P1 + pb1) @ P2 + pb2
    k_mm<64, 128, true ><<<dim3(782, 1), dim3(128), 0, stream>>>(emb, p1h, p1l, pb1, bufT, N, 128, 128);
    k_mm<64, 128, false><<<dim3(782, 1), dim3(128), 0, stream>>>(bufT, p2h, p2l, pb2, z, N, 128, 128);
}

// Round 10
// 346.626 us; speedup vs baseline: 2.6942x; 1.0790x over previous
//
#include <hip/hip_runtime.h>
#include <hip/hip_bf16.h>
#include <cstdint>
#include <cstddef>

#define NN 50000
#define NE 800000
#define NRBP 3128   // padded row-chunk count: ceil(50000/16) -> mult of 8
#define NBK 196     // coarse buckets: dest >> 8
#define BKCAP 4608  // bucket capacity (mean 4082 + 8 sigma)

typedef __attribute__((ext_vector_type(8))) short bf16x8;
typedef __attribute__((ext_vector_type(4))) float f32x4;

#define OUT_BF16ROW 0
#define OUT_FRAG    1
#define OUT_F32     2

static __device__ __forceinline__ unsigned short f2bf_u(float f) {
    __hip_bfloat16 h = __float2bfloat16(f);
    return *reinterpret_cast<unsigned short*>(&h);
}
static __device__ __forceinline__ float bfu2f(unsigned short u) {
    __hip_bfloat16 h = *reinterpret_cast<__hip_bfloat16*>(&u);
    return __bfloat162float(h);
}

// async global->LDS, 16B per lane. lds dst must be wave-uniform (HW adds lane*16).
static __device__ __forceinline__ void gll16(void* lds_dst, const void* gsrc) {
    __builtin_amdgcn_global_load_lds(
        (const __attribute__((address_space(1))) void*)gsrc,
        (__attribute__((address_space(3))) void*)lds_dst, 16, 0, 0);
}

// ========== CSR build: padded-bucket direct scatter (no pre-scan) ==========

// scatter edges into fixed-capacity bucket slots. Packed: x = src | (dlow<<20), y = val.
__global__ __launch_bounds__(256) void k_bscat(const int* __restrict__ erow,
                                               const int* __restrict__ ecol,
                                               const float* __restrict__ eval_,
                                               int* __restrict__ gcur,
                                               int2* __restrict__ tmp, int e) {
    __shared__ int lcnt[NBK], lbase[NBK], lcur[NBK];
    int tid = threadIdx.x;
    for (int t = tid; t < NBK; t += 256) { lcnt[t] = 0; lcur[t] = 0; }
    __syncthreads();
    int d_[4], b_[4];
#pragma unroll
    for (int q = 0; q < 4; ++q) {
        int i = blockIdx.x * 1024 + q * 256 + tid;
        d_[q] = -1;
        if (i < e) {
            d_[q] = ecol[i];
            b_[q] = d_[q] >> 8;
            atomicAdd(&lcnt[b_[q]], 1);
        }
    }
    __syncthreads();
    for (int t = tid; t < NBK; t += 256)
        lbase[t] = lcnt[t] ? (t * BKCAP + atomicAdd(&gcur[t], lcnt[t])) : 0;
    __syncthreads();
#pragma unroll
    for (int q = 0; q < 4; ++q) {
        int i = blockIdx.x * 1024 + q * 256 + tid;
        if (i < e) {
            int b = b_[q];
            int pos = lbase[b] + atomicAdd(&lcur[b], 1);
            tmp[pos] = make_int2(erow[i] | ((d_[q] & 255) << 20), __float_as_int(eval_[i]));
        }
    }
}

// block per bucket: LDS histogram over 256 in-bucket dests -> rowrange(beg,end),
// deg/dinv, then scatter to final CSR position within the bucket's padded window.
__global__ __launch_bounds__(256) void k_bsort(const int2* __restrict__ tmp,
                                               const int* __restrict__ cnt,
                                               int2* __restrict__ rowrange,
                                               float* __restrict__ dinv,
                                               int2* __restrict__ epk) {
    __shared__ int lcnt[256], lcur[256];
    __shared__ float ldeg[256];
    __shared__ int wsum[4];
    int tid = threadIdx.x;
    int b = blockIdx.x;
    int base = b * BKCAP, endb = base + cnt[b];
    lcnt[tid] = 0;
    ldeg[tid] = 0.f;
    __syncthreads();
    for (int i = base + tid; i < endb; i += 256) {
        int2 e2 = tmp[i];
        int d = e2.x >> 20;
        atomicAdd(&lcnt[d], 1);
        atomicAdd(&ldeg[d], __int_as_float(e2.y));
    }
    __syncthreads();
    int v = lcnt[tid];
    int lane = tid & 63, w = tid >> 6;
    int incl = v;
#pragma unroll
    for (int d = 1; d < 64; d <<= 1) {
        int t = __shfl_up(incl, d);
        if (lane >= d) incl += t;
    }
    if (lane == 63) wsum[w] = incl;
    __syncthreads();
    int woff = 0;
    for (int j = 0; j < w; ++j) woff += wsum[j];
    int ex = woff + incl - v;
    int dest = (b << 8) + tid;
    if (dest < NN) {
        rowrange[dest] = make_int2(base + ex, base + ex + v);
        dinv[dest] = rsqrtf(1.f + ldeg[tid]);
    }
    lcur[tid] = ex;
    __syncthreads();
    for (int i = base + tid; i < endb; i += 256) {
        int2 e2 = tmp[i];
        int d = e2.x >> 20;
        int pos = base + atomicAdd(&lcur[d], 1);
        epk[pos] = make_int2(e2.x & 0xFFFFF, e2.y);
    }
}

// epk.y := raw_val * dinv[src]  (dst factor applied in agg). Padded iteration.
__global__ void k_normw(int2* __restrict__ epk, const float* __restrict__ dinv,
                        const int* __restrict__ cnt) {
    int i = blockIdx.x * 256 + threadIdx.x;
    if (i >= NBK * BKCAP) return;
    int b = i / BKCAP;
    if (i - b * BKCAP < cnt[b]) {
        int2 pk = epk[i];
        epk[i].y = __float_as_int(__int_as_float(pk.y) * dinv[pk.x]);
    }
}

// ---------------- sparse aggregation: wave-per-row, shfl indices, 8x MLP --------
// out[i,:] = dinv_i * ( dinv_i*H[i,:] + sum_e w'_e * H[src_e,:] ) + bias  (opt relu)
// OMODE: 0 = fp32 row-major; 1 = frag-layout bf16 (DIM=256); 2 = both (DIM=128).
template<int DIM, bool RELU, int OMODE>
__global__ __launch_bounds__(256) void k_agg(const unsigned short* __restrict__ H,
                      const int2* __restrict__ rowrange, const int2* __restrict__ epk,
                      const float* __restrict__ dinv, const float* __restrict__ bias,
                      float* __restrict__ outf, unsigned short* __restrict__ oh) {
    constexpr int WU = DIM / 128;  // uints per lane
    int lane = threadIdx.x & 63;
    int row = blockIdx.x * 4 + (threadIdx.x >> 6);
    if (row >= NN) return;

    const uint2* H2 = reinterpret_cast<const uint2*>(H);
    const unsigned* H1 = reinterpret_cast<const unsigned*>(H);

    auto loadrow = [&](int r, unsigned* v) {
        if constexpr (WU == 2) {
            uint2 t = H2[(size_t)r * 64 + lane];
            v[0] = t.x; v[1] = t.y;
        } else {
            v[0] = H1[(size_t)r * 64 + lane];
        }
    };

    float di = dinv[row];
    float acc[WU * 2];
    {
        unsigned sv[WU];
        loadrow(row, sv);
#pragma unroll
        for (int w2 = 0; w2 < WU; ++w2) {
            acc[w2 * 2 + 0] = di * __uint_as_float(sv[w2] << 16);
            acc[w2 * 2 + 1] = di * __uint_as_float(sv[w2] & 0xffff0000u);
        }
    }

    auto accum = [&](const unsigned* v, float wt) {
#pragma unroll
        for (int w2 = 0; w2 < WU; ++w2) {
            acc[w2 * 2 + 0] += wt * __uint_as_float(v[w2] << 16);
            acc[w2 * 2 + 1] += wt * __uint_as_float(v[w2] & 0xffff0000u);
        }
    };

    int2 rr = rowrange[row];
    int beg = rr.x, end = rr.y;
    for (int c = beg; c < end; c += 64) {
        int m = min(64, end - c);
        int2 pk = make_int2(0, 0);
        if (c + lane < end) pk = epk[c + lane];
        int j = 0;
        for (; j + 8 <= m; j += 8) {
            int s[8];
            float wv[8];
#pragma unroll
            for (int q = 0; q < 8; ++q) {
                s[q] = __shfl(pk.x, j + q);
                wv[q] = __int_as_float(__shfl(pk.y, j + q));
            }
            unsigned g[8][WU];
#pragma unroll
            for (int q = 0; q < 8; ++q) loadrow(s[q], g[q]);
#pragma unroll
            for (int q = 0; q < 8; ++q) accum(g[q], wv[q]);
        }
        for (; j < m; ++j) {
            int s = __shfl(pk.x, j);
            float wt = __int_as_float(__shfl(pk.y, j));
            unsigned g[WU];
            loadrow(s, g);
            accum(g, wt);
        }
    }

    if constexpr (OMODE == 1) {
        // DIM==256: lane owns cols 4*lane..4*lane+3
        float4 b4 = reinterpret_cast<const float4*>(bias)[lane];
        float o0 = acc[0] * di + b4.x;
        float o1 = acc[1] * di + b4.y;
        float o2 = acc[2] * di + b4.z;
        float o3 = acc[3] * di + b4.w;
        if (RELU) {
            o0 = fmaxf(o0, 0.f); o1 = fmaxf(o1, 0.f);
            o2 = fmaxf(o2, 0.f); o3 = fmaxf(o3, 0.f);
        }
        ushort4 h;
        h.x = f2bf_u(o0); h.y = f2bf_u(o1); h.z = f2bf_u(o2); h.w = f2bf_u(o3);
        size_t ch = (size_t)(lane >> 3) * NRBP + (row >> 4);
        int off = ((lane & 7) >> 1) * 128 + (row & 15) * 8 + (lane & 1) * 4;
        *reinterpret_cast<ushort4*>(&oh[ch * 512 + off]) = h;
    } else if constexpr (WU == 2) {
        float4 b4 = reinterpret_cast<const float4*>(bias)[lane];
        float4 o;
        o.x = acc[0] * di + b4.x; o.y = acc[1] * di + b4.y;
        o.z = acc[2] * di + b4.z; o.w = acc[3] * di + b4.w;
        if (RELU) {
            o.x = fmaxf(o.x, 0.f); o.y = fmaxf(o.y, 0.f);
            o.z = fmaxf(o.z, 0.f); o.w = fmaxf(o.w, 0.f);
        }
        reinterpret_cast<float4*>(outf)[(size_t)row * 64 + lane] = o;
    } else {
        // DIM==128: lane owns cols 2*lane, 2*lane+1
        float2 b2 = reinterpret_cast<const float2*>(bias)[lane];
        float o0 = acc[0] * di + b2.x;
        float o1 = acc[1] * di + b2.y;
        if (RELU) { o0 = fmaxf(o0, 0.f); o1 = fmaxf(o1, 0.f); }
        reinterpret_cast<float2*>(outf)[(size_t)row * 64 + lane] = make_float2(o0, o1);
        if constexpr (OMODE == 2) {
            // also emit frag-layout bf16 plane (A for head GEMM, K=128)
            int c0 = 2 * lane;
            int kb = c0 >> 5, kg = (c0 & 31) >> 3, kj = c0 & 7;
            size_t ch = (size_t)kb * NRBP + (row >> 4);
            int off = kg * 128 + (row & 15) * 8 + kj;
            ushort2 h2s;
            h2s.x = f2bf_u(o0); h2s.y = f2bf_u(o1);
            *reinterpret_cast<ushort2*>(&oh[ch * 512 + off]) = h2s;
        }
    }
}

// ---------------- pre-split x (fp32 [N][256]) into frag-layout bf16 (hi only) ----
__global__ void k_xsplit(const float* __restrict__ X, unsigned short* __restrict__ xh,
                         int nrows) {
    int idx = blockIdx.x * 256 + threadIdx.x;
    int row = idx >> 6, t = idx & 63;
    if (row >= nrows) return;
    float4 v = *reinterpret_cast<const float4*>(&X[(size_t)row * 256 + t * 4]);
    ushort4 h;
    h.x = f2bf_u(v.x); h.y = f2bf_u(v.y); h.z = f2bf_u(v.z); h.w = f2bf_u(v.w);
    size_t chunk = (size_t)(t >> 3) * NRBP + (row >> 4);
    int off = ((t & 7) >> 1) * 128 + (row & 15) * 8 + (t & 1) * 4;
    *reinterpret_cast<ushort4*>(&xh[chunk * 512 + off]) = h;
}

// ---------------- weight pre-split into frag-ordered hi/lo bf16 ----------------
// layout: [kb=K/32][nb=M/16] chunks of 512 shorts: [kg=4][c=16][kj=8]
__global__ void k_wsplit(const float* __restrict__ W, unsigned short* __restrict__ wh,
                         unsigned short* __restrict__ wl, int K, int M) {
    int idx = blockIdx.x * blockDim.x + threadIdx.x;
    if (idx >= K * M) return;
    int k = idx / M, m = idx % M;
    float w = W[idx];
    unsigned short h = f2bf_u(w);
    float hf = bfu2f(h);
    unsigned short lo = f2bf_u(w - hf);
    int kb = k >> 5, kg = (k & 31) >> 3, kj = k & 7;
    int nb = m >> 4, c = m & 15;
    int off = (kb * (M >> 4) + nb) * 512 + kg * 128 + c * 8 + kj;
    wh[off] = h;
    wl[off] = lo;
}

// ----- pipelined MFMA GEMM: A = bf16 frag plane (hi), W = hi/lo, 2-pass ---------
// OMODE: 0 = bf16 row-major out; 1 = frag bf16 out (+bias/relu); 2 = fp32 out (+bias).
template<int BM, int BN, int OMODE, bool RELU>
__global__ __launch_bounds__((BM / 64) * (BN / 64) * 64)
void k_mmf(const unsigned short* __restrict__ ah,
           const unsigned short* __restrict__ wh, const unsigned short* __restrict__ wl,
           const float* __restrict__ bias, void* __restrict__ Cout,
           int nrows, int K, int M) {
    constexpr int NW = (BM / 64) * (BN / 64);
    constexpr int WN = BN / 64;
    constexpr int AC = BM / 16, BC = BN / 16;
    constexpr int TC = AC + 2 * BC;
    constexpr int BUF = TC * 512;  // shorts
    __shared__ unsigned short sm[2 * BUF];
    const int tid = threadIdx.x, l = tid & 63, wid = tid >> 6;
    const int wr = wid / WN, wc = wid % WN;
    const int bm = blockIdx.x * BM, bn = blockIdx.y * BN;
    const int rb0 = blockIdx.x * AC, nb0 = blockIdx.y * BC;
    const int NKB = K >> 5, MB = M >> 4;
    const int fo = (l >> 4) * 128 + (l & 15) * 8;
    f32x4 acc[4][4] = {};

    auto stage = [&](int buf, int kb) {
        unsigned short* base = sm + buf * BUF;
        const unsigned short* ga_h = ah + ((size_t)kb * NRBP + rb0) * 512;
        const unsigned short* gb_h = wh + ((size_t)kb * MB + nb0) * 512;
        const unsigned short* gb_l = wl + ((size_t)kb * MB + nb0) * 512;
        for (int q = wid; q < TC; q += NW) {
            const unsigned short* s;
            if (q < AC) s = ga_h + q * 512;
            else if (q < AC + BC) s = gb_h + (q - AC) * 512;
            else s = gb_l + (q - AC - BC) * 512;
            gll16(base + q * 512, s + l * 8);
        }
    };

    stage(0, 0);
    __syncthreads();
    for (int kb = 0; kb < NKB; ++kb) {
        const int cur = kb & 1;
        if (kb + 1 < NKB) stage(cur ^ 1, kb + 1);
        const unsigned short* base = sm + cur * BUF;
        bf16x8 a_h[4], b_h[4], b_l[4];
#pragma unroll
        for (int i = 0; i < 4; ++i)
            a_h[i] = *reinterpret_cast<const bf16x8*>(base + (wr * 4 + i) * 512 + fo);
#pragma unroll
        for (int j = 0; j < 4; ++j) {
            b_h[j] = *reinterpret_cast<const bf16x8*>(base + (AC + wc * 4 + j) * 512 + fo);
            b_l[j] = *reinterpret_cast<const bf16x8*>(base + (AC + BC + wc * 4 + j) * 512 + fo);
        }
#pragma unroll
        for (int i = 0; i < 4; ++i)
#pragma unroll
            for (int j = 0; j < 4; ++j) {
                acc[i][j] = __builtin_amdgcn_mfma_f32_16x16x32_bf16(a_h[i], b_h[j], acc[i][j], 0, 0, 0);
                acc[i][j] = __builtin_amdgcn_mfma_f32_16x16x32_bf16(a_h[i], b_l[j], acc[i][j], 0, 0, 0);
            }
        __syncthreads();
    }
#pragma unroll
    for (int j = 0; j < 4; ++j) {
        int col = bn + wc * 64 + j * 16 + (l & 15);
        float bv = (OMODE != OUT_BF16ROW) ? bias[col] : 0.f;
#pragma unroll
        for (int i = 0; i < 4; ++i) {
            int row0 = bm + wr * 64 + i * 16 + (l >> 4) * 4;
#pragma unroll
            for (int r = 0; r < 4; ++r) {
                int row = row0 + r;
                if (row >= nrows) continue;
                float v = acc[i][j][r] + bv;
                if (RELU) v = fmaxf(v, 0.f);
                if constexpr (OMODE == OUT_BF16ROW) {
                    ((unsigned short*)Cout)[(size_t)row * M + col] = f2bf_u(v);
                } else if constexpr (OMODE == OUT_FRAG) {
                    size_t ch = (size_t)(col >> 5) * NRBP + (row >> 4);
                    int off = ((col & 31) >> 3) * 128 + (row & 15) * 8 + (col & 7);
                    ((unsigned short*)Cout)[ch * 512 + off] = f2bf_u(v);
                } else {
                    ((float*)Cout)[(size_t)row * M + col] = v;
                }
            }
        }
    }
}

// ---------------- launch ----------------

extern "C" void kernel_launch(void* const* d_in, const int* in_sizes, int n_in,
                              void* d_out, int out_size, void* d_ws, size_t ws_size,
                              hipStream_t stream) {
    const float* x        = (const float*)d_in[0];
    const int*   edge_row = (const int*)d_in[1];
    const int*   edge_col = (const int*)d_in[2];
    const float* edge_val = (const float*)d_in[3];
    const float* W1  = (const float*)d_in[4];
    const float* b1  = (const float*)d_in[5];
    const float* W2  = (const float*)d_in[6];
    const float* b2  = (const float*)d_in[7];
    const float* W3  = (const float*)d_in[8];
    const float* b3  = (const float*)d_in[9];
    const float* P1  = (const float*)d_in[10];
    const float* pb1 = (const float*)d_in[11];
    const float* P2  = (const float*)d_in[12];
    const float* pb2 = (const float*)d_in[13];

    const int N = NN, E = NE;
    const size_t EPAD = (size_t)NBK * BKCAP;  // 903168

    uintptr_t p = (uintptr_t)d_ws;
    auto alloc = [&](size_t bytes) -> void* {
        void* r = (void*)p;
        p += (bytes + 255) & ~(size_t)255;
        return r;
    };
    float* dinv     = (float*)alloc((size_t)N * 4);
    int2*  rowrange = (int2*)alloc((size_t)N * 8);
    int*   gcur     = (int*)alloc(256 * 4);
    int2*  etmp     = (int2*)alloc(EPAD * 8);
    int2*  epk      = (int2*)alloc(EPAD * 8);
    unsigned short* Hbf = (unsigned short*)alloc((size_t)N * 256 * 2);
    const size_t PLANE8 = (size_t)8 * NRBP * 512 * 2;  // K=256 A-plane bytes
    const size_t PLANE4 = (size_t)4 * NRBP * 512 * 2;  // K=128 A-plane bytes
    unsigned short* pAh   = (unsigned short*)alloc(PLANE8);
    unsigned short* pBh   = (unsigned short*)alloc(PLANE8);
    unsigned short* embF  = (unsigned short*)alloc(PLANE4);
    unsigned short* bufTF = (unsigned short*)alloc(PLANE4);
    unsigned short* wf1h = (unsigned short*)alloc(65536 * 2);
    unsigned short* wf1l = (unsigned short*)alloc(65536 * 2);
    unsigned short* wf2h = (unsigned short*)alloc(65536 * 2);
    unsigned short* wf2l = (unsigned short*)alloc(65536 * 2);
    unsigned short* wf3h = (unsigned short*)alloc(32768 * 2);
    unsigned short* wf3l = (unsigned short*)alloc(32768 * 2);
    unsigned short* p1h  = (unsigned short*)alloc(16384 * 2);
    unsigned short* p1l  = (unsigned short*)alloc(16384 * 2);
    unsigned short* p2h  = (unsigned short*)alloc(16384 * 2);
    unsigned short* p2l  = (unsigned short*)alloc(16384 * 2);

    float* emb = (float*)d_out;
    float* z   = (float*)d_out + (size_t)N * 128;

    dim3 b256(256);
    const int gE1k = (E + 1023) / 1024;  // 782

    // weight/x splits (independent)
    k_wsplit<<<dim3(256), b256, 0, stream>>>(W1, wf1h, wf1l, 256, 256);
    k_wsplit<<<dim3(256), b256, 0, stream>>>(W2, wf2h, wf2l, 256, 256);
    k_wsplit<<<dim3(128), b256, 0, stream>>>(W3, wf3h, wf3l, 256, 128);
    k_wsplit<<<dim3(64),  b256, 0, stream>>>(P1, p1h, p1l, 128, 128);
    k_wsplit<<<dim3(64),  b256, 0, stream>>>(P2, p2h, p2l, 128, 128);
    k_xsplit<<<dim3((N * 64 + 255) / 256), b256, 0, stream>>>(x, pAh, N);

    // CSR build: direct padded-bucket scatter -> in-bucket sort(+deg) -> normalize
    hipMemsetAsync(gcur, 0, 256 * 4, stream);
    k_bscat<<<dim3(gE1k), b256, 0, stream>>>(edge_row, edge_col, edge_val, gcur, etmp, E);
    k_bsort<<<dim3(NBK), b256, 0, stream>>>(etmp, gcur, rowrange, dinv, epk);
    k_normw<<<dim3((int)((EPAD + 255) / 256)), b256, 0, stream>>>(epk, dinv, gcur);

    const int gagg = (N + 3) / 4;  // 12500

    // layer 1: Hbf = x @ W1 ; pBh = bf16(relu(agg(Hbf)*dinv + b1)) frag layout
    k_mmf<128, 128, OUT_BF16ROW, false><<<dim3(391, 2), dim3(256), 0, stream>>>(
        pAh, wf1h, wf1l, nullptr, Hbf, N, 256, 256);
    k_agg<256, true, 1><<<dim3(gagg), b256, 0, stream>>>(Hbf, rowrange, epk, dinv, b1, nullptr, pBh);
    // layer 2
    k_mmf<128, 128, OUT_BF16ROW, false><<<dim3(391, 2), dim3(256), 0, stream>>>(
        pBh, wf2h, wf2l, nullptr, Hbf, N, 256, 256);
    k_agg<256, true, 1><<<dim3(gagg), b256, 0, stream>>>(Hbf, rowrange, epk, dinv, b2, nullptr, pAh);
    // layer 3: emb (fp32 out) + embF (frag bf16 plane for head)
    k_mmf<64, 128, OUT_BF16ROW, false><<<dim3(782, 1), dim3(128), 0, stream>>>(
        pAh, wf3h, wf3l, nullptr, Hbf, N, 256, 128);
    k_agg<128, false, 2><<<dim3(gagg), b256, 0, stream>>>(Hbf, rowrange, epk, dinv, b3, emb, embF);
    // head: z = relu(emb @ P1 + pb1) @ P2 + pb2  (all MFMA frag path)
    k_mmf<64, 128, OUT_FRAG, true><<<dim3(782, 1), dim3(128), 0, stream>>>(
        embF, p1h, p1l, pb1, bufTF, N, 128, 128);
    k_mmf<64, 128, OUT_F32, false><<<dim3(782, 1), dim3(128), 0, stream>>>(
        bufTF, p2h, p2l, pb2, z, N, 128, 128);
}

// Round 11
// 329.465 us; speedup vs baseline: 2.8345x; 1.0521x over previous
//
#include <hip/hip_runtime.h>
#include <hip/hip_bf16.h>
#include <cstdint>
#include <cstddef>

#define NN 50000
#define NE 800000
#define NRBP 3128   // padded row-chunk count: ceil(50000/16) -> mult of 8
#define NBK 196     // coarse buckets: dest >> 8
#define BKCAP 4608  // bucket capacity (mean 4082 + 8 sigma)

typedef __attribute__((ext_vector_type(8))) short bf16x8;
typedef __attribute__((ext_vector_type(4))) float f32x4;

#define OUT_BF16ROW 0
#define OUT_FRAG    1
#define OUT_F32     2

static __device__ __forceinline__ unsigned short f2bf_u(float f) {
    __hip_bfloat16 h = __float2bfloat16(f);
    return *reinterpret_cast<unsigned short*>(&h);
}
static __device__ __forceinline__ float bfu2f(unsigned short u) {
    __hip_bfloat16 h = *reinterpret_cast<__hip_bfloat16*>(&u);
    return __bfloat162float(h);
}

// async global->LDS, 16B per lane. lds dst must be wave-uniform (HW adds lane*16).
static __device__ __forceinline__ void gll16(void* lds_dst, const void* gsrc) {
    __builtin_amdgcn_global_load_lds(
        (const __attribute__((address_space(1))) void*)gsrc,
        (__attribute__((address_space(3))) void*)lds_dst, 16, 0, 0);
}

// ========== merged prep: x frag-split + 5 weight hi/lo splits + gcur zero =======
// blocks [0,12500): xsplit; [12500,13268): weight splits. Block 12500 zeroes gcur.
__global__ __launch_bounds__(256) void k_prep(
        const float* __restrict__ X,
        const float* __restrict__ W1, const float* __restrict__ W2,
        const float* __restrict__ W3, const float* __restrict__ P1,
        const float* __restrict__ P2,
        unsigned short* __restrict__ xh,
        unsigned short* __restrict__ w1h, unsigned short* __restrict__ w1l,
        unsigned short* __restrict__ w2h, unsigned short* __restrict__ w2l,
        unsigned short* __restrict__ w3h, unsigned short* __restrict__ w3l,
        unsigned short* __restrict__ p1h, unsigned short* __restrict__ p1l,
        unsigned short* __restrict__ p2h, unsigned short* __restrict__ p2l,
        int* __restrict__ gcur) {
    int b = blockIdx.x;
    int tid = threadIdx.x;
    if (b < 12500) {
        int idx = b * 256 + tid;
        int row = idx >> 6, t = idx & 63;
        if (row < NN) {
            float4 v = *reinterpret_cast<const float4*>(&X[(size_t)row * 256 + t * 4]);
            ushort4 h;
            h.x = f2bf_u(v.x); h.y = f2bf_u(v.y); h.z = f2bf_u(v.z); h.w = f2bf_u(v.w);
            size_t chunk = (size_t)(t >> 3) * NRBP + (row >> 4);
            int off = ((t & 7) >> 1) * 128 + (row & 15) * 8 + (t & 1) * 4;
            *reinterpret_cast<ushort4*>(&xh[chunk * 512 + off]) = h;
        }
        return;
    }
    int wb = b - 12500;
    if (wb == 0) gcur[tid] = 0;  // zero bucket cursors (256 ints)
    const float* W;
    unsigned short *wh, *wl;
    int K, M;
    if (wb < 256)      { W = W1; wh = w1h; wl = w1l; K = 256; M = 256; }
    else if (wb < 512) { W = W2; wh = w2h; wl = w2l; K = 256; M = 256; wb -= 256; }
    else if (wb < 640) { W = W3; wh = w3h; wl = w3l; K = 256; M = 128; wb -= 512; }
    else if (wb < 704) { W = P1; wh = p1h; wl = p1l; K = 128; M = 128; wb -= 640; }
    else               { W = P2; wh = p2h; wl = p2l; K = 128; M = 128; wb -= 704; }
    int idx = wb * 256 + tid;
    if (idx >= K * M) return;
    int k = idx / M, m = idx % M;
    float w = W[idx];
    unsigned short h = f2bf_u(w);
    unsigned short lo = f2bf_u(w - bfu2f(h));
    int kb = k >> 5, kg = (k & 31) >> 3, kj = k & 7;
    int nb = m >> 4, c = m & 15;
    int off = (kb * (M >> 4) + nb) * 512 + kg * 128 + c * 8 + kj;
    wh[off] = h;
    wl[off] = lo;
}

// ========== CSR build: padded-bucket direct scatter (no pre-scan) ==========

__global__ __launch_bounds__(256) void k_bscat(const int* __restrict__ erow,
                                               const int* __restrict__ ecol,
                                               const float* __restrict__ eval_,
                                               int* __restrict__ gcur,
                                               int2* __restrict__ tmp, int e) {
    __shared__ int lcnt[NBK], lbase[NBK], lcur[NBK];
    int tid = threadIdx.x;
    for (int t = tid; t < NBK; t += 256) { lcnt[t] = 0; lcur[t] = 0; }
    __syncthreads();
    int d_[4], b_[4];
#pragma unroll
    for (int q = 0; q < 4; ++q) {
        int i = blockIdx.x * 1024 + q * 256 + tid;
        d_[q] = -1;
        if (i < e) {
            d_[q] = ecol[i];
            b_[q] = d_[q] >> 8;
            atomicAdd(&lcnt[b_[q]], 1);
        }
    }
    __syncthreads();
    for (int t = tid; t < NBK; t += 256)
        lbase[t] = lcnt[t] ? (t * BKCAP + atomicAdd(&gcur[t], lcnt[t])) : 0;
    __syncthreads();
#pragma unroll
    for (int q = 0; q < 4; ++q) {
        int i = blockIdx.x * 1024 + q * 256 + tid;
        if (i < e) {
            int b = b_[q];
            int pos = lbase[b] + atomicAdd(&lcur[b], 1);
            tmp[pos] = make_int2(erow[i] | ((d_[q] & 255) << 20), __float_as_int(eval_[i]));
        }
    }
}

// block per bucket: LDS histogram over 256 in-bucket dests -> rowrange(beg,end),
// deg/dinv, then scatter to final CSR position within the bucket's padded window.
__global__ __launch_bounds__(256) void k_bsort(const int2* __restrict__ tmp,
                                               const int* __restrict__ cnt,
                                               int2* __restrict__ rowrange,
                                               float* __restrict__ dinv,
                                               int2* __restrict__ epk) {
    __shared__ int lcnt[256], lcur[256];
    __shared__ float ldeg[256];
    __shared__ int wsum[4];
    int tid = threadIdx.x;
    int b = blockIdx.x;
    int base = b * BKCAP, endb = base + cnt[b];
    lcnt[tid] = 0;
    ldeg[tid] = 0.f;
    __syncthreads();
    for (int i = base + tid; i < endb; i += 256) {
        int2 e2 = tmp[i];
        int d = e2.x >> 20;
        atomicAdd(&lcnt[d], 1);
        atomicAdd(&ldeg[d], __int_as_float(e2.y));
    }
    __syncthreads();
    int v = lcnt[tid];
    int lane = tid & 63, w = tid >> 6;
    int incl = v;
#pragma unroll
    for (int d = 1; d < 64; d <<= 1) {
        int t = __shfl_up(incl, d);
        if (lane >= d) incl += t;
    }
    if (lane == 63) wsum[w] = incl;
    __syncthreads();
    int woff = 0;
    for (int j = 0; j < w; ++j) woff += wsum[j];
    int ex = woff + incl - v;
    int dest = (b << 8) + tid;
    if (dest < NN) {
        rowrange[dest] = make_int2(base + ex, base + ex + v);
        dinv[dest] = rsqrtf(1.f + ldeg[tid]);
    }
    lcur[tid] = ex;
    __syncthreads();
    for (int i = base + tid; i < endb; i += 256) {
        int2 e2 = tmp[i];
        int d = e2.x >> 20;
        int pos = base + atomicAdd(&lcur[d], 1);
        epk[pos] = make_int2(e2.x & 0xFFFFF, e2.y);
    }
}

// epk.y := raw_val * dinv[src]  (dst factor applied in agg). Padded iteration.
__global__ void k_normw(int2* __restrict__ epk, const float* __restrict__ dinv,
                        const int* __restrict__ cnt) {
    int i = blockIdx.x * 256 + threadIdx.x;
    if (i >= NBK * BKCAP) return;
    int b = i / BKCAP;
    if (i - b * BKCAP < cnt[b]) {
        int2 pk = epk[i];
        epk[i].y = __float_as_int(__int_as_float(pk.y) * dinv[pk.x]);
    }
}

// ---------------- sparse aggregation: wave-per-row, shfl indices, 4x MLP --------
// out[i,:] = dinv_i * ( dinv_i*H[i,:] + sum_e w'_e * H[src_e,:] ) + bias  (opt relu)
// OMODE: 0 = fp32 row-major; 1 = frag-layout bf16 (DIM=256); 2 = both (DIM=128).
template<int DIM, bool RELU, int OMODE>
__global__ __launch_bounds__(256) void k_agg(const unsigned short* __restrict__ H,
                      const int2* __restrict__ rowrange, const int2* __restrict__ epk,
                      const float* __restrict__ dinv, const float* __restrict__ bias,
                      float* __restrict__ outf, unsigned short* __restrict__ oh) {
    constexpr int WU = DIM / 128;  // uints per lane
    int lane = threadIdx.x & 63;
    int row = blockIdx.x * 4 + (threadIdx.x >> 6);
    if (row >= NN) return;

    const uint2* H2 = reinterpret_cast<const uint2*>(H);
    const unsigned* H1 = reinterpret_cast<const unsigned*>(H);

    auto loadrow = [&](int r, unsigned* v) {
        if constexpr (WU == 2) {
            uint2 t = H2[(size_t)r * 64 + lane];
            v[0] = t.x; v[1] = t.y;
        } else {
            v[0] = H1[(size_t)r * 64 + lane];
        }
    };

    float di = dinv[row];
    float acc[WU * 2];
    {
        unsigned sv[WU];
        loadrow(row, sv);
#pragma unroll
        for (int w2 = 0; w2 < WU; ++w2) {
            acc[w2 * 2 + 0] = di * __uint_as_float(sv[w2] << 16);
            acc[w2 * 2 + 1] = di * __uint_as_float(sv[w2] & 0xffff0000u);
        }
    }

    auto accum = [&](const unsigned* v, float wt) {
#pragma unroll
        for (int w2 = 0; w2 < WU; ++w2) {
            acc[w2 * 2 + 0] += wt * __uint_as_float(v[w2] << 16);
            acc[w2 * 2 + 1] += wt * __uint_as_float(v[w2] & 0xffff0000u);
        }
    };

    int2 rr = rowrange[row];
    int beg = rr.x, end = rr.y;
    for (int c = beg; c < end; c += 64) {
        int m = min(64, end - c);
        int2 pk = make_int2(0, 0);
        if (c + lane < end) pk = epk[c + lane];
        int j = 0;
        for (; j + 4 <= m; j += 4) {
            int s0 = __shfl(pk.x, j + 0), s1 = __shfl(pk.x, j + 1);
            int s2 = __shfl(pk.x, j + 2), s3 = __shfl(pk.x, j + 3);
            float w0 = __int_as_float(__shfl(pk.y, j + 0));
            float w1 = __int_as_float(__shfl(pk.y, j + 1));
            float w2 = __int_as_float(__shfl(pk.y, j + 2));
            float w3 = __int_as_float(__shfl(pk.y, j + 3));
            unsigned g0[WU], g1[WU], g2[WU], g3[WU];
            loadrow(s0, g0);
            loadrow(s1, g1);
            loadrow(s2, g2);
            loadrow(s3, g3);
            accum(g0, w0);
            accum(g1, w1);
            accum(g2, w2);
            accum(g3, w3);
        }
        for (; j < m; ++j) {
            int s = __shfl(pk.x, j);
            float wt = __int_as_float(__shfl(pk.y, j));
            unsigned g[WU];
            loadrow(s, g);
            accum(g, wt);
        }
    }

    if constexpr (OMODE == 1) {
        // DIM==256: lane owns cols 4*lane..4*lane+3
        float4 b4 = reinterpret_cast<const float4*>(bias)[lane];
        float o0 = acc[0] * di + b4.x;
        float o1 = acc[1] * di + b4.y;
        float o2 = acc[2] * di + b4.z;
        float o3 = acc[3] * di + b4.w;
        if (RELU) {
            o0 = fmaxf(o0, 0.f); o1 = fmaxf(o1, 0.f);
            o2 = fmaxf(o2, 0.f); o3 = fmaxf(o3, 0.f);
        }
        ushort4 h;
        h.x = f2bf_u(o0); h.y = f2bf_u(o1); h.z = f2bf_u(o2); h.w = f2bf_u(o3);
        size_t ch = (size_t)(lane >> 3) * NRBP + (row >> 4);
        int off = ((lane & 7) >> 1) * 128 + (row & 15) * 8 + (lane & 1) * 4;
        *reinterpret_cast<ushort4*>(&oh[ch * 512 + off]) = h;
    } else if constexpr (WU == 2) {
        float4 b4 = reinterpret_cast<const float4*>(bias)[lane];
        float4 o;
        o.x = acc[0] * di + b4.x; o.y = acc[1] * di + b4.y;
        o.z = acc[2] * di + b4.z; o.w = acc[3] * di + b4.w;
        if (RELU) {
            o.x = fmaxf(o.x, 0.f); o.y = fmaxf(o.y, 0.f);
            o.z = fmaxf(o.z, 0.f); o.w = fmaxf(o.w, 0.f);
        }
        reinterpret_cast<float4*>(outf)[(size_t)row * 64 + lane] = o;
    } else {
        // DIM==128: lane owns cols 2*lane, 2*lane+1
        float2 b2 = reinterpret_cast<const float2*>(bias)[lane];
        float o0 = acc[0] * di + b2.x;
        float o1 = acc[1] * di + b2.y;
        if (RELU) { o0 = fmaxf(o0, 0.f); o1 = fmaxf(o1, 0.f); }
        reinterpret_cast<float2*>(outf)[(size_t)row * 64 + lane] = make_float2(o0, o1);
        if constexpr (OMODE == 2) {
            // also emit frag-layout bf16 plane (A for head GEMM, K=128)
            int c0 = 2 * lane;
            int kb = c0 >> 5, kg = (c0 & 31) >> 3, kj = c0 & 7;
            size_t ch = (size_t)kb * NRBP + (row >> 4);
            int off = kg * 128 + (row & 15) * 8 + kj;
            ushort2 h2s;
            h2s.x = f2bf_u(o0); h2s.y = f2bf_u(o1);
            *reinterpret_cast<ushort2*>(&oh[ch * 512 + off]) = h2s;
        }
    }
}

// ----- pipelined MFMA GEMM: A = bf16 frag plane (hi), W = hi/lo, 2-pass ---------
// OMODE: 0 = bf16 row-major out; 1 = frag bf16 out (+bias/relu); 2 = fp32 out (+bias).
template<int BM, int BN, int OMODE, bool RELU>
__global__ __launch_bounds__((BM / 64) * (BN / 64) * 64)
void k_mmf(const unsigned short* __restrict__ ah,
           const unsigned short* __restrict__ wh, const unsigned short* __restrict__ wl,
           const float* __restrict__ bias, void* __restrict__ Cout,
           int nrows, int K, int M) {
    constexpr int NW = (BM / 64) * (BN / 64);
    constexpr int WN = BN / 64;
    constexpr int AC = BM / 16, BC = BN / 16;
    constexpr int TC = AC + 2 * BC;
    constexpr int BUF = TC * 512;  // shorts
    __shared__ unsigned short sm[2 * BUF];
    const int tid = threadIdx.x, l = tid & 63, wid = tid >> 6;
    const int wr = wid / WN, wc = wid % WN;
    const int bm = blockIdx.x * BM, bn = blockIdx.y * BN;
    const int rb0 = blockIdx.x * AC, nb0 = blockIdx.y * BC;
    const int NKB = K >> 5, MB = M >> 4;
    const int fo = (l >> 4) * 128 + (l & 15) * 8;
    f32x4 acc[4][4] = {};

    auto stage = [&](int buf, int kb) {
        unsigned short* base = sm + buf * BUF;
        const unsigned short* ga_h = ah + ((size_t)kb * NRBP + rb0) * 512;
        const unsigned short* gb_h = wh + ((size_t)kb * MB + nb0) * 512;
        const unsigned short* gb_l = wl + ((size_t)kb * MB + nb0) * 512;
        for (int q = wid; q < TC; q += NW) {
            const unsigned short* s;
            if (q < AC) s = ga_h + q * 512;
            else if (q < AC + BC) s = gb_h + (q - AC) * 512;
            else s = gb_l + (q - AC - BC) * 512;
            gll16(base + q * 512, s + l * 8);
        }
    };

    stage(0, 0);
    __syncthreads();
    for (int kb = 0; kb < NKB; ++kb) {
        const int cur = kb & 1;
        if (kb + 1 < NKB) stage(cur ^ 1, kb + 1);
        const unsigned short* base = sm + cur * BUF;
        bf16x8 a_h[4], b_h[4], b_l[4];
#pragma unroll
        for (int i = 0; i < 4; ++i)
            a_h[i] = *reinterpret_cast<const bf16x8*>(base + (wr * 4 + i) * 512 + fo);
#pragma unroll
        for (int j = 0; j < 4; ++j) {
            b_h[j] = *reinterpret_cast<const bf16x8*>(base + (AC + wc * 4 + j) * 512 + fo);
            b_l[j] = *reinterpret_cast<const bf16x8*>(base + (AC + BC + wc * 4 + j) * 512 + fo);
        }
#pragma unroll
        for (int i = 0; i < 4; ++i)
#pragma unroll
            for (int j = 0; j < 4; ++j) {
                acc[i][j] = __builtin_amdgcn_mfma_f32_16x16x32_bf16(a_h[i], b_h[j], acc[i][j], 0, 0, 0);
                acc[i][j] = __builtin_amdgcn_mfma_f32_16x16x32_bf16(a_h[i], b_l[j], acc[i][j], 0, 0, 0);
            }
        __syncthreads();
    }
#pragma unroll
    for (int j = 0; j < 4; ++j) {
        int col = bn + wc * 64 + j * 16 + (l & 15);
        float bv = (OMODE != OUT_BF16ROW) ? bias[col] : 0.f;
#pragma unroll
        for (int i = 0; i < 4; ++i) {
            int row0 = bm + wr * 64 + i * 16 + (l >> 4) * 4;
#pragma unroll
            for (int r = 0; r < 4; ++r) {
                int row = row0 + r;
                if (row >= nrows) continue;
                float v = acc[i][j][r] + bv;
                if (RELU) v = fmaxf(v, 0.f);
                if constexpr (OMODE == OUT_BF16ROW) {
                    ((unsigned short*)Cout)[(size_t)row * M + col] = f2bf_u(v);
                } else if constexpr (OMODE == OUT_FRAG) {
                    size_t ch = (size_t)(col >> 5) * NRBP + (row >> 4);
                    int off = ((col & 31) >> 3) * 128 + (row & 15) * 8 + (col & 7);
                    ((unsigned short*)Cout)[ch * 512 + off] = f2bf_u(v);
                } else {
                    ((float*)Cout)[(size_t)row * M + col] = v;
                }
            }
        }
    }
}

// ---------------- launch ----------------

extern "C" void kernel_launch(void* const* d_in, const int* in_sizes, int n_in,
                              void* d_out, int out_size, void* d_ws, size_t ws_size,
                              hipStream_t stream) {
    const float* x        = (const float*)d_in[0];
    const int*   edge_row = (const int*)d_in[1];
    const int*   edge_col = (const int*)d_in[2];
    const float* edge_val = (const float*)d_in[3];
    const float* W1  = (const float*)d_in[4];
    const float* b1  = (const float*)d_in[5];
    const float* W2  = (const float*)d_in[6];
    const float* b2  = (const float*)d_in[7];
    const float* W3  = (const float*)d_in[8];
    const float* b3  = (const float*)d_in[9];
    const float* P1  = (const float*)d_in[10];
    const float* pb1 = (const float*)d_in[11];
    const float* P2  = (const float*)d_in[12];
    const float* pb2 = (const float*)d_in[13];

    const int N = NN, E = NE;
    const size_t EPAD = (size_t)NBK * BKCAP;  // 903168

    uintptr_t p = (uintptr_t)d_ws;
    auto alloc = [&](size_t bytes) -> void* {
        void* r = (void*)p;
        p += (bytes + 255) & ~(size_t)255;
        return r;
    };
    float* dinv     = (float*)alloc((size_t)N * 4);
    int2*  rowrange = (int2*)alloc((size_t)N * 8);
    int*   gcur     = (int*)alloc(256 * 4);
    int2*  etmp     = (int2*)alloc(EPAD * 8);
    int2*  epk      = (int2*)alloc(EPAD * 8);
    unsigned short* Hbf = (unsigned short*)alloc((size_t)N * 256 * 2);
    const size_t PLANE8 = (size_t)8 * NRBP * 512 * 2;  // K=256 A-plane bytes
    const size_t PLANE4 = (size_t)4 * NRBP * 512 * 2;  // K=128 A-plane bytes
    unsigned short* pAh   = (unsigned short*)alloc(PLANE8);
    unsigned short* pBh   = (unsigned short*)alloc(PLANE8);
    unsigned short* embF  = (unsigned short*)alloc(PLANE4);
    unsigned short* bufTF = (unsigned short*)alloc(PLANE4);
    unsigned short* wf1h = (unsigned short*)alloc(65536 * 2);
    unsigned short* wf1l = (unsigned short*)alloc(65536 * 2);
    unsigned short* wf2h = (unsigned short*)alloc(65536 * 2);
    unsigned short* wf2l = (unsigned short*)alloc(65536 * 2);
    unsigned short* wf3h = (unsigned short*)alloc(32768 * 2);
    unsigned short* wf3l = (unsigned short*)alloc(32768 * 2);
    unsigned short* p1h  = (unsigned short*)alloc(16384 * 2);
    unsigned short* p1l  = (unsigned short*)alloc(16384 * 2);
    unsigned short* p2h  = (unsigned short*)alloc(16384 * 2);
    unsigned short* p2l  = (unsigned short*)alloc(16384 * 2);

    float* emb = (float*)d_out;
    float* z   = (float*)d_out + (size_t)N * 128;

    dim3 b256(256);
    const int gE1k = (E + 1023) / 1024;  // 782

    // merged prep: xsplit (12500 blocks) + 5 wsplits (768) + gcur zero
    k_prep<<<dim3(12500 + 768), b256, 0, stream>>>(
        x, W1, W2, W3, P1, P2, pAh,
        wf1h, wf1l, wf2h, wf2l, wf3h, wf3l, p1h, p1l, p2h, p2l, gcur);

    // CSR build: direct padded-bucket scatter -> in-bucket sort(+deg) -> normalize
    k_bscat<<<dim3(gE1k), b256, 0, stream>>>(edge_row, edge_col, edge_val, gcur, etmp, E);
    k_bsort<<<dim3(NBK), b256, 0, stream>>>(etmp, gcur, rowrange, dinv, epk);
    k_normw<<<dim3((int)((EPAD + 255) / 256)), b256, 0, stream>>>(epk, dinv, gcur);

    const int gagg = (N + 3) / 4;  // 12500

    // layer 1: Hbf = x @ W1 ; pBh = bf16(relu(agg(Hbf)*dinv + b1)) frag layout
    k_mmf<128, 128, OUT_BF16ROW, false><<<dim3(391, 2), dim3(256), 0, stream>>>(
        pAh, wf1h, wf1l, nullptr, Hbf, N, 256, 256);
    k_agg<256, true, 1><<<dim3(gagg), b256, 0, stream>>>(Hbf, rowrange, epk, dinv, b1, nullptr, pBh);
    // layer 2
    k_mmf<128, 128, OUT_BF16ROW, false><<<dim3(391, 2), dim3(256), 0, stream>>>(
        pBh, wf2h, wf2l, nullptr, Hbf, N, 256, 256);
    k_agg<256, true, 1><<<dim3(gagg), b256, 0, stream>>>(Hbf, rowrange, epk, dinv, b2, nullptr, pAh);
    // layer 3: emb (fp32 out) + embF (frag bf16 plane for head)
    k_mmf<64, 128, OUT_BF16ROW, false><<<dim3(782, 1), dim3(128), 0, stream>>>(
        pAh, wf3h, wf3l, nullptr, Hbf, N, 256, 128);
    k_agg<128, false, 2><<<dim3(gagg), b256, 0, stream>>>(Hbf, rowrange, epk, dinv, b3, emb, embF);
    // head: z = relu(emb @ P1 + pb1) @ P2 + pb2  (all MFMA frag path)
    k_mmf<64, 128, OUT_FRAG, true><<<dim3(782, 1), dim3(128), 0, stream>>>(
        embF, p1h, p1l, pb1, bufTF, N, 128, 128);
    k_mmf<64, 128, OUT_F32, false><<<dim3(782, 1), dim3(128), 0, stream>>>(
        bufTF, p2h, p2l, pb2, z, N, 128, 128);
}